// Round 10
// baseline (427.032 us; speedup 1.0000x reference)
//
#include <hip/hip_runtime.h>
#include <math.h>

#define N 1024
#define NN (N*N)
#define NE 32768

// ---------------- workspace layout (floats) ----------------
#define OFF_A    ((size_t)0)
#define OFF_H10  ((size_t)(5*NN))
#define OFF_M0   ((size_t)(5*NN))
#define OFF_CSR  ((size_t)(7*NN))
#define OFF_BT   ((size_t)(9*NN))
#define OFF_M1   ((size_t)(10*NN))
#define OFF_AN   ((size_t)(11*NN))
#define OFF_H20  ((size_t)(13*NN))
#define OFF_H21  (OFF_H20 + 264196)
#define OFF_SC   (OFF_H21 + 264196)
// scalar vectors (1024 each)
#define SC_D0a 0
#define SC_F0a 1024
#define SC_D1a 2048
#define SC_F1a 3072
#define SC_D0b 4096
#define SC_F0b 5120
#define SC_D1b 6144
#define SC_F1b 7168
#define SC_D1c 8192
#define SC_F1c 9216
#define SC_D2  10240
#define SC_F2  11264
#define SC_DEG 12288
#define SC_DGV 13312
#define OFF_XW1  (OFF_SC + 14336)
#define OFF_HB   (OFF_XW1 + 65536)
#define OFF_HW2  (OFF_HB + 65536)

#define CSR_STRIDE 96
#define CSRF (1024 * CSR_STRIDE)
#define CSC_MAXT 80

// ---------------- edge scatter ----------------
__global__ void k_scatter5(const int* __restrict__ e0, const int* __restrict__ e1,
                           const int* __restrict__ e2, const int* __restrict__ e3,
                           const int* __restrict__ e4, float* __restrict__ A) {
  int g = blockIdx.x * 256 + threadIdx.x;
  int seg = g >> 15;
  int k = g & 32767;
  const int* e = (seg == 0) ? e0 : (seg == 1) ? e1 : (seg == 2) ? e2 : (seg == 3) ? e3 : e4;
  atomicAdd(&A[(size_t)seg * NN + (size_t)e[k] * N + e[NE + k]], 1.0f);
}

// ---------------- conv1 (pad=1)+relu+maxpool2: 2 pooled px/thread, vector LDS reads ----------------
// tile: 32 pooled wide x 16 pooled high; input [L][34][68] (66 used, stride 68 for 16B align)
template<int L>
__device__ __forceinline__ void conv1_body(const float* __restrict__ A,
    const float* __restrict__ W, const float* __restrict__ Bn, float* __restrict__ out,
    float* __restrict__ smem) {
  float* sIn = smem;                       // L*34*68
  float* sW  = smem + L * 34 * 68;         // 16*L*9
  float* sB  = sW + 16 * L * 9;            // 16
  const int tid = threadIdx.x;
  for (int i = tid; i < 16 * L * 9; i += 256) sW[i] = W[i];
  if (tid < 16) sB[tid] = Bn[tid];
  const int px0 = blockIdx.x * 32;
  const int py0 = blockIdx.y * 16;
  const int x0 = 2 * px0 - 1;
  const int y0 = 2 * py0 - 1;
  for (int l = 0; l < L; ++l)
    for (int idx = tid; idx < 34 * 68; idx += 256) {
      int r = idx / 68, c = idx - r * 68;
      int iy = y0 + r, ix = x0 + c;
      sIn[(l * 34 + r) * 68 + c] = (c < 66 && iy >= 0 && iy < N && ix >= 0 && ix < N)
                                   ? A[(size_t)l * NN + (size_t)iy * N + ix] : 0.f;
    }
  __syncthreads();
  const int tx = tid & 15, ty = tid >> 4;
  float p[L][4][6];
  #pragma unroll
  for (int l = 0; l < L; ++l)
    #pragma unroll
    for (int r = 0; r < 4; ++r) {
      const float* src = &sIn[((l * 34) + (2 * ty + r)) * 68 + 4 * tx];
      float4 a = *(const float4*)src;
      float2 b = *(const float2*)(src + 4);
      p[l][r][0] = a.x; p[l][r][1] = a.y; p[l][r][2] = a.z; p[l][r][3] = a.w;
      p[l][r][4] = b.x; p[l][r][5] = b.y;
    }
  const size_t obase = (size_t)(py0 + ty) * 512 + px0 + 2 * tx;
  for (int oc = 0; oc < 16; ++oc) {
    float wr[L * 9];
    #pragma unroll
    for (int t = 0; t < L * 9; ++t) wr[t] = sW[oc * L * 9 + t];
    float m0 = -1e30f, m1 = -1e30f;
    #pragma unroll
    for (int dy = 0; dy < 2; ++dy)
      #pragma unroll
      for (int dxp = 0; dxp < 4; ++dxp) {
        float s = 0.f;
        #pragma unroll
        for (int l = 0; l < L; ++l)
          #pragma unroll
          for (int ky = 0; ky < 3; ++ky)
            #pragma unroll
            for (int kx = 0; kx < 3; ++kx)
              s = fmaf(p[l][dy + ky][dxp + kx], wr[l * 9 + ky * 3 + kx], s);
        if (dxp < 2) m0 = fmaxf(m0, s); else m1 = fmaxf(m1, s);
      }
    float2 o2;
    o2.x = fmaxf(m0 + sB[oc], 0.f);
    o2.y = fmaxf(m1 + sB[oc], 0.f);
    *(float2*)&out[(size_t)oc * 262144 + obase] = o2;
  }
}

__global__ __launch_bounds__(256) void k_conv1_both(const float* __restrict__ Ab,
    const float* __restrict__ W0, const float* __restrict__ b0,
    const float* __restrict__ W1, const float* __restrict__ b1, float* __restrict__ H1b) {
  __shared__ float smem[3 * 34 * 68 + 16 * 3 * 9 + 16];
  if (blockIdx.z == 0) conv1_body<2>(Ab, W0, b0, H1b, smem);
  else                 conv1_body<3>(Ab + 2 * NN, W1, b1, H1b + 4 * NN, smem);
}

// ---------------- conv2 (pad=2)+relu+maxpool2: 2 pooled px/thread, per-ic staging ----------------
// tile: 32 pooled wide x 16 pooled high; input [36][68] per ic (stride 68, 16B aligned)
__global__ __launch_bounds__(256) void k_conv2_both(const float* __restrict__ H1b,
    const float* __restrict__ W0, const float* __restrict__ b0,
    const float* __restrict__ W1, const float* __restrict__ b1,
    float* __restrict__ H2_0, float* __restrict__ H2_1) {
  const int z = blockIdx.z;
  const float* in = H1b + (size_t)z * 4 * NN;
  const float* W  = z ? W1 : W0;
  const float* Bn = z ? b1 : b0;
  float* out = z ? H2_1 : H2_0;
  __shared__ float sIn[36 * 68];
  __shared__ float sW[4 * 16 * 9];
  __shared__ float sB[4];
  const int tid = threadIdx.x;
  for (int i = tid; i < 4 * 16 * 9; i += 256) sW[i] = W[i];
  if (tid < 4) sB[tid] = Bn[tid];
  const int px0 = blockIdx.x * 32;
  const int py0 = blockIdx.y * 16;
  const int x0 = 2 * px0 - 2;
  const int y0 = 2 * py0 - 2;
  const int tx = tid & 15, ty = tid >> 4;
  float acc[4][2][4];   // [oc][dy][dxp] pre-pool accumulators
  #pragma unroll
  for (int oc = 0; oc < 4; ++oc)
    #pragma unroll
    for (int dy = 0; dy < 2; ++dy)
      #pragma unroll
      for (int dxp = 0; dxp < 4; ++dxp) acc[oc][dy][dxp] = 0.f;
  for (int g = 0; g < 16; ++g) {
    __syncthreads();
    for (int idx = tid; idx < 36 * 68; idx += 256) {
      int r = idx / 68, c = idx - r * 68;
      int iy = y0 + r, ix = x0 + c;
      sIn[r * 68 + c] = (c < 66 && iy >= 0 && iy < 512 && ix >= 0 && ix < 512)
                        ? in[(size_t)g * 262144 + (size_t)iy * 512 + ix] : 0.f;
    }
    __syncthreads();
    float q[4][6];
    #pragma unroll
    for (int r = 0; r < 4; ++r) {
      const float* src = &sIn[(2 * ty + r) * 68 + 4 * tx];
      float4 a = *(const float4*)src;
      float2 b = *(const float2*)(src + 4);
      q[r][0] = a.x; q[r][1] = a.y; q[r][2] = a.z; q[r][3] = a.w;
      q[r][4] = b.x; q[r][5] = b.y;
    }
    #pragma unroll
    for (int oc = 0; oc < 4; ++oc) {
      float wr[9];
      #pragma unroll
      for (int t = 0; t < 9; ++t) wr[t] = sW[oc * 144 + g * 9 + t];
      #pragma unroll
      for (int dy = 0; dy < 2; ++dy)
        #pragma unroll
        for (int dxp = 0; dxp < 4; ++dxp) {
          float s = acc[oc][dy][dxp];
          #pragma unroll
          for (int ky = 0; ky < 3; ++ky)
            #pragma unroll
            for (int kx = 0; kx < 3; ++kx)
              s = fmaf(q[dy + ky][dxp + kx], wr[ky * 3 + kx], s);
          acc[oc][dy][dxp] = s;
        }
    }
  }
  const int oy = py0 + ty;
  const int ox0 = px0 + 2 * tx;
  if (oy < 257) {
    #pragma unroll
    for (int oc = 0; oc < 4; ++oc) {
      float m0 = fmaxf(fmaxf(acc[oc][0][0], acc[oc][0][1]), fmaxf(acc[oc][1][0], acc[oc][1][1]));
      float m1 = fmaxf(fmaxf(acc[oc][0][2], acc[oc][0][3]), fmaxf(acc[oc][1][2], acc[oc][1][3]));
      if (ox0 < 257)     out[(size_t)oc * 66049 + (size_t)oy * 257 + ox0]     = fmaxf(m0 + sB[oc], 0.f);
      if (ox0 + 1 < 257) out[(size_t)oc * 66049 + (size_t)oy * 257 + ox0 + 1] = fmaxf(m1 + sB[oc], 0.f);
    }
  }
}

// ---------------- fused tconv1+relu + tconv2+sigmoid + attended (A *= att), both blocks ----------------
__global__ __launch_bounds__(256) void k_tc_both(
    const float* __restrict__ H2_0, const float* __restrict__ H2_1,
    const float* __restrict__ t1w0, const float* __restrict__ t1b0,
    const float* __restrict__ t2w0, const float* __restrict__ t2b0,
    const float* __restrict__ t1w1, const float* __restrict__ t1b1,
    const float* __restrict__ t2w1, const float* __restrict__ t2b1,
    float* __restrict__ Ab) {
  const int z = blockIdx.z;
  const int L = 2 + z;
  const float* in  = z ? H2_1 : H2_0;
  const float* W1p = z ? t1w1 : t1w0;
  const float* B1p = z ? t1b1 : t1b0;
  const float* W2p = z ? t2w1 : t2w0;
  const float* B2p = z ? t2b1 : t2b0;
  float* A = Ab + (size_t)z * 2 * NN;
  __shared__ float sW1[256], sB1[16], sW2[192], sB2[3];
  int tid = threadIdx.y * 16 + threadIdx.x;
  sW1[tid] = W1p[tid];
  if (tid < 16) sB1[tid] = B1p[tid];
  for (int i = tid; i < L * 64; i += 256) sW2[i] = W2p[i];
  if (tid < L) sB2[tid] = B2p[tid];
  __syncthreads();
  const int n = blockIdx.x * 16 + threadIdx.x;   // 0..511
  const int m = blockIdx.y * 16 + threadIdx.y;   // 0..511
  const int p = m >> 1, q = n >> 1;
  const int f1y = 1 - (m & 1), f1x = 1 - (n & 1);
  float vin[4];
  #pragma unroll
  for (int ci = 0; ci < 4; ++ci) vin[ci] = in[(size_t)ci * 66049 + (size_t)p * 257 + q];
  float v[16];
  #pragma unroll
  for (int c = 0; c < 16; ++c) {
    float s = sB1[c];
    #pragma unroll
    for (int ci = 0; ci < 4; ++ci)
      s = fmaf(vin[ci], sW1[c * 16 + ci * 4 + f1y * 2 + f1x], s);
    v[c] = fmaxf(s, 0.f);
  }
  for (int l = 0; l < L; ++l) {
    #pragma unroll
    for (int dy = 0; dy < 2; ++dy)
      #pragma unroll
      for (int dx = 0; dx < 2; ++dx) {
        float s = sB2[l];
        #pragma unroll
        for (int c = 0; c < 16; ++c)
          s = fmaf(v[c], sW2[l * 64 + c * 4 + (1 - dy) * 2 + (1 - dx)], s);
        float sg = 1.f / (1.f + expf(-s));
        size_t idx = (size_t)l * NN + (size_t)(2 * m + dy) * N + (2 * n + dx);
        A[idx] *= sg;
      }
  }
}

// ---------------- extract: CSR of y=0..3, entry-major CSC of y=4 (A12); deg of y=0,2 ----------------
__global__ __launch_bounds__(256) void k_extract(const float* __restrict__ Ab,
    int* __restrict__ gcol, float* __restrict__ gval, int* __restrict__ gcnt,
    int* __restrict__ crowT, float* __restrict__ cvalT, int* __restrict__ ccnt,
    float* __restrict__ DEGACC,
    float* __restrict__ D0a, float* __restrict__ F0a,
    float* __restrict__ D1a, float* __restrict__ F1a) {
  const int row = blockIdx.x;
  const int y = blockIdx.y;                 // 0:A00 1:A01 2:A10 3:A11 4:A12
  const float* base = Ab + (size_t)y * NN + (size_t)row * N;
  __shared__ int cnt;
  __shared__ float sdiag;
  __shared__ float red[4];
  if (threadIdx.x == 0) cnt = 0;
  __syncthreads();
  const int j4 = threadIdx.x;
  float4 v = ((const float4*)base)[j4];
  if (j4 == (row >> 2)) sdiag = ((const float*)&v)[row & 3];
  if (y == 4) {
    if (threadIdx.x == 0) DEGACC[row] = 0.f;
    #pragma unroll
    for (int t = 0; t < 4; ++t) {
      float x = ((const float*)&v)[t];
      if (x != 0.f) {
        int j = 4 * j4 + t;
        int p = atomicAdd(&ccnt[j], 1);
        if (p < CSC_MAXT) { crowT[p * 1024 + j] = row; cvalT[p * 1024 + j] = x; }
      }
    }
    return;
  }
  const size_t rb = ((size_t)y * 1024 + row) * CSR_STRIDE;
  #pragma unroll
  for (int t = 0; t < 4; ++t) {
    float x = ((const float*)&v)[t];
    if (x != 0.f) {
      int p = atomicAdd(&cnt, 1);
      if (p < CSR_STRIDE) { gcol[rb + p] = 4 * j4 + t; gval[rb + p] = x; }
    }
  }
  float s = v.x + v.y + v.z + v.w;
  #pragma unroll
  for (int o = 32; o > 0; o >>= 1) s += __shfl_down(s, o, 64);
  if ((threadIdx.x & 63) == 0) red[threadIdx.x >> 6] = s;
  __syncthreads();
  if (threadIdx.x == 0) {
    gcnt[(size_t)y * 1024 + row] = (cnt < CSR_STRIDE) ? cnt : CSR_STRIDE;
    if (y == 0 || y == 2) {
      float tot = red[0] + red[1] + red[2] + red[3];
      float fl = (sdiag == 0.f) ? 1.f : 0.f;
      float deg = tot + fl;
      float* D = (y == 0) ? D0a : D1a;
      float* F = (y == 0) ? F0a : F1a;
      D[row] = (deg > 0.f) ? (1.f / sqrtf(deg)) : 0.f;
      F[row] = fl;
    }
  }
}

// ---------------- hop-1 double-sparse SpMM ----------------
__global__ __launch_bounds__(256) void k_spmm(
    const int* __restrict__ gcol, const float* __restrict__ gval, const int* __restrict__ gcnt,
    const float* __restrict__ D0a, const float* __restrict__ F0a,
    const float* __restrict__ D1a, const float* __restrict__ F1a,
    float* __restrict__ M0, float* __restrict__ BT,
    float* __restrict__ D0b, float* __restrict__ F0b,
    float* __restrict__ D1b, float* __restrict__ F1b) {
  const int row = blockIdx.x;
  const int y = blockIdx.y;
  const int lm = y * 2, rm = y * 2 + 1;
  const float* Da = y ? D1a : D0a;
  const float* Fa = y ? F1a : F0a;
  __shared__ __align__(16) float acc[1024];
  __shared__ int lcol[112];
  __shared__ float lw[112];
  __shared__ int lrc[112];
  __shared__ int cl;
  __shared__ float red[4];
  __shared__ float sdiag;
  ((float4*)acc)[threadIdx.x] = make_float4(0.f, 0.f, 0.f, 0.f);
  const float di = Da[row];
  const int cnt_l = gcnt[(size_t)lm * 1024 + row];
  const size_t lb = ((size_t)lm * 1024 + row) * CSR_STRIDE;
  if (threadIdx.x < cnt_l) {
    int k = gcol[lb + threadIdx.x];
    lcol[threadIdx.x] = k;
    lw[threadIdx.x] = di * gval[lb + threadIdx.x] * Da[k];
    lrc[threadIdx.x] = gcnt[(size_t)rm * 1024 + k];
  }
  if (threadIdx.x == 0) {
    int c = cnt_l;
    if (Fa[row] != 0.f) {
      lcol[c] = row; lw[c] = di * di; lrc[c] = gcnt[(size_t)rm * 1024 + row]; ++c;
    }
    cl = c;
  }
  __syncthreads();
  const int sub = threadIdx.x >> 5, lane = threadIdx.x & 31;
  const int cle = cl;
  for (int e = sub; e < cle; e += 8) {
    const int k = lcol[e];
    const float w = lw[e];
    const int rc = lrc[e];
    const size_t rbv = ((size_t)rm * 1024 + k) * CSR_STRIDE;
    for (int t = lane; t < rc; t += 32)
      atomicAdd(&acc[gcol[rbv + t]], w * gval[rbv + t]);
  }
  __syncthreads();
  float4 o = ((const float4*)acc)[threadIdx.x];
  float* C = y ? BT : M0;
  ((float4*)(C + (size_t)row * N))[threadIdx.x] = o;
  if (threadIdx.x == (row >> 2)) sdiag = ((const float*)&o)[row & 3];
  float s = o.x + o.y + o.z + o.w;
  #pragma unroll
  for (int off = 32; off > 0; off >>= 1) s += __shfl_down(s, off, 64);
  if ((threadIdx.x & 63) == 0) red[threadIdx.x >> 6] = s;
  __syncthreads();
  if (threadIdx.x == 0) {
    float tot = red[0] + red[1] + red[2] + red[3];
    float fl = (sdiag == 0.f) ? 1.f : 0.f;
    float deg = tot + fl;
    float* D = y ? D1b : D0b;
    float* F = y ? F1b : F0b;
    D[row] = (deg > 0.f) ? (1.f / sqrtf(deg)) : 0.f;
    F[row] = fl;
  }
}

// ---------------- hop-2: 8 rows x 256 cols per block; CSC amortized over 8 rows ----------------
__global__ __launch_bounds__(256) void k_spmm2(const float* __restrict__ BT,
    const float* __restrict__ D1b, const float* __restrict__ F1b,
    const int* __restrict__ crowT, const float* __restrict__ cvalT, const int* __restrict__ ccnt,
    float* __restrict__ M1, float* __restrict__ DEGACC, float* __restrict__ DIAGV) {
  const int g0 = blockIdx.x << 3;
  const int j  = (blockIdx.y << 8) + threadIdx.x;
  __shared__ float bt[1024 * 9];
  __shared__ float wsum[4][8];
  const int tid = threadIdx.x;
  for (int kq = 0; kq < 4; ++kq) {
    const int k = (kq << 8) + tid;
    const float dv = D1b[k];
    #pragma unroll
    for (int row = 0; row < 8; ++row)
      bt[k * 9 + row] = BT[(size_t)(g0 + row) * N + k] * dv;
  }
  __syncthreads();
  if (tid < 8) {
    const int gr = g0 + tid;
    bt[gr * 9 + tid] += F1b[gr] * D1b[gr];
  }
  __syncthreads();
  int cn = ccnt[j];
  cn = min(cn, CSC_MAXT);
  float o[8];
  #pragma unroll
  for (int row = 0; row < 8; ++row) o[row] = 0.f;
  for (int t = 0; t < cn; ++t) {
    const int   r = crowT[t * 1024 + j];
    const float v = cvalT[t * 1024 + j];
    const int rb = r * 9;
    #pragma unroll
    for (int row = 0; row < 8; ++row)
      o[row] = fmaf(bt[rb + row], v, o[row]);
  }
  #pragma unroll
  for (int row = 0; row < 8; ++row) o[row] *= D1b[g0 + row];
  #pragma unroll
  for (int row = 0; row < 8; ++row)
    M1[(size_t)(g0 + row) * N + j] = o[row];
  if ((unsigned)(j - g0) < 8u) DIAGV[j] = o[j - g0];
  #pragma unroll
  for (int row = 0; row < 8; ++row) {
    float s = o[row];
    #pragma unroll
    for (int off = 32; off > 0; off >>= 1) s += __shfl_down(s, off, 64);
    if ((tid & 63) == 0) wsum[tid >> 6][row] = s;
  }
  __syncthreads();
  if (tid < 8) {
    float p = wsum[0][tid] + wsum[1][tid] + wsum[2][tid] + wsum[3][tid];
    atomicAdd(&DEGACC[g0 + tid], p);
  }
}

// ---------------- finish deg of M1 ----------------
__global__ void k_fin(const float* __restrict__ DEGACC, const float* __restrict__ DIAGV,
                      float* __restrict__ D1c, float* __restrict__ F1c) {
  const int row = blockIdx.x * 256 + threadIdx.x;
  const float fl = (DIAGV[row] == 0.f) ? 1.f : 0.f;
  const float deg = DEGACC[row] + fl;
  D1c[row] = (deg > 0.f) ? (1.f / sqrtf(deg)) : 0.f;
  F1c[row] = fl;
}

// ---------------- fused max(scale0(M0), scale1(M1)) + deg of result ----------------
__global__ __launch_bounds__(256) void k_maxdeg(const float* __restrict__ M0,
    const float* __restrict__ d0, const float* __restrict__ f0,
    const float* __restrict__ M1, const float* __restrict__ d1, const float* __restrict__ f1,
    float* __restrict__ Aout, float* __restrict__ dinv2, float* __restrict__ dflg2) {
  const int row = blockIdx.x;
  const int j4 = threadIdx.x;
  const float r0 = d0[row], r1 = d1[row];
  const float fl0 = f0[row], fl1 = f1[row];
  float4 a = ((const float4*)(M0 + (size_t)row * N))[j4];
  float4 b = ((const float4*)(M1 + (size_t)row * N))[j4];
  const float4 c0 = ((const float4*)d0)[j4];
  const float4 c1 = ((const float4*)d1)[j4];
  int d = row - 4 * j4;
  if ((unsigned)d < 4u) { ((float*)&a)[d] += fl0; ((float*)&b)[d] += fl1; }
  float4 o;
  o.x = fmaxf(a.x * r0 * c0.x, b.x * r1 * c1.x);
  o.y = fmaxf(a.y * r0 * c0.y, b.y * r1 * c1.y);
  o.z = fmaxf(a.z * r0 * c0.z, b.z * r1 * c1.z);
  o.w = fmaxf(a.w * r0 * c0.w, b.w * r1 * c1.w);
  ((float4*)(Aout + (size_t)row * N))[j4] = o;
  __shared__ float sdiag;
  if ((unsigned)d < 4u) sdiag = ((float*)&o)[d];
  float s = o.x + o.y + o.z + o.w;
  #pragma unroll
  for (int off = 32; off > 0; off >>= 1) s += __shfl_down(s, off, 64);
  __shared__ float red[4];
  if ((threadIdx.x & 63) == 0) red[threadIdx.x >> 6] = s;
  __syncthreads();
  if (threadIdx.x == 0) {
    float tot = red[0] + red[1] + red[2] + red[3];
    float fl = (sdiag == 0.0f) ? 1.0f : 0.0f;
    float deg = tot + fl;
    dinv2[row] = (deg > 0.0f) ? (1.0f / sqrtf(deg)) : 0.0f;
    dflg2[row] = fl;
  }
}

// ---------------- skinny matmul ----------------
template<int K, int NCOL, bool BIAS, bool RELU>
__global__ void k_mm_small(const float* __restrict__ A, const float* __restrict__ B,
                           const float* __restrict__ bias, float* __restrict__ out) {
  const int j = threadIdx.x;
  const int i = blockIdx.x * blockDim.y + threadIdx.y;
  const float* ar = A + (size_t)i * K;
  float acc = 0.f;
  #pragma unroll 8
  for (int k = 0; k < K; ++k) acc = fmaf(ar[k], B[(size_t)k * NCOL + j], acc);
  if (BIAS) acc += bias[j];
  if (RELU) acc = fmaxf(acc, 0.f);
  out[(size_t)i * NCOL + j] = acc;
}

// ---------------- skinny matmul with fused An normalization ----------------
template<int NCOL, bool RELU>
__global__ void k_an_mm(const float* __restrict__ BT, const float* __restrict__ dinv,
                        const float* __restrict__ dflg, const float* __restrict__ Bm,
                        const float* __restrict__ bias, float* __restrict__ out) {
  const int j = threadIdx.x;
  const int i = blockIdx.x * blockDim.y + threadIdx.y;
  const float di = dinv[i];
  const float* ar = BT + (size_t)i * N;
  float acc = 0.f;
  for (int k = 0; k < N; k += 4) {
    float4 a4 = *(const float4*)&ar[k];
    float4 d4 = *(const float4*)&dinv[k];
    acc = fmaf(a4.x * d4.x, Bm[(size_t)(k + 0) * NCOL + j], acc);
    acc = fmaf(a4.y * d4.y, Bm[(size_t)(k + 1) * NCOL + j], acc);
    acc = fmaf(a4.z * d4.z, Bm[(size_t)(k + 2) * NCOL + j], acc);
    acc = fmaf(a4.w * d4.w, Bm[(size_t)(k + 3) * NCOL + j], acc);
  }
  acc = fmaf(dflg[i] * dinv[i], Bm[(size_t)i * NCOL + j], acc);
  acc = fmaf(di, acc, bias[j]);
  if (RELU) acc = fmaxf(acc, 0.f);
  out[(size_t)i * NCOL + j] = acc;
}

// ---------------- launcher ----------------
extern "C" void kernel_launch(void* const* d_in, const int* in_sizes, int n_in,
                              void* d_out, int out_size, void* d_ws, size_t ws_size,
                              hipStream_t stream) {
  const float* x     = (const float*)d_in[0];
  const float* w1    = (const float*)d_in[22];
  const float* bias1 = (const float*)d_in[23];
  const float* w2    = (const float*)d_in[24];
  const float* bias2 = (const float*)d_in[25];
  float* out = (float*)d_out;
  float* ws  = (float*)d_ws;

  float* A    = ws + OFF_A;
  float* H1   = ws + OFF_H10;
  float* M0   = ws + OFF_M0;
  float* BT   = ws + OFF_BT;
  float* M1   = ws + OFF_M1;
  float* AN   = ws + OFF_AN;
  float* H2_0 = ws + OFF_H20;
  float* H2_1 = ws + OFF_H21;
  int*   gcol  = (int*)(ws + OFF_CSR);
  float* gval  = ws + OFF_CSR + (size_t)4 * CSRF;
  int*   gcnt  = (int*)(ws + OFF_CSR + (size_t)8 * CSRF);
  int*   crowT = (int*)(ws + OFF_CSR + (size_t)8 * CSRF + 4096);
  float* cvalT = ws + OFF_CSR + (size_t)8 * CSRF + 4096 + CSC_MAXT * 1024;
  int*   ccnt  = (int*)(ws + OFF_CSR + (size_t)8 * CSRF + 4096 + (size_t)2 * CSC_MAXT * 1024);
  float* SC   = ws + OFF_SC;
  float *D0a = SC + SC_D0a, *F0a = SC + SC_F0a, *D1a = SC + SC_D1a, *F1a = SC + SC_F1a;
  float *D0b = SC + SC_D0b, *F0b = SC + SC_F0b, *D1b = SC + SC_D1b, *F1b = SC + SC_F1b;
  float *D1c = SC + SC_D1c, *F1c = SC + SC_F1c, *D2 = SC + SC_D2, *F2 = SC + SC_F2;
  float *DEGACC = SC + SC_DEG, *DIAGV = SC + SC_DGV;
  float* XW1 = ws + OFF_XW1;
  float* HB  = ws + OFF_HB;
  float* HW2 = ws + OFF_HW2;

  hipMemsetAsync(A, 0, (size_t)5 * NN * sizeof(float), stream);

  dim3 b256(256), b16(16, 16);
  // independent: x @ w1
  k_mm_small<128, 64, false, false><<<256, dim3(64, 4), 0, stream>>>(x, w1, nullptr, XW1);

  k_scatter5<<<640, b256, 0, stream>>>((const int*)d_in[1], (const int*)d_in[2],
                                       (const int*)d_in[3], (const int*)d_in[4],
                                       (const int*)d_in[5], A);

  // attention encoders
  k_conv1_both<<<dim3(16, 32, 2), b256, 0, stream>>>(A,
      (const float*)d_in[6], (const float*)d_in[7],
      (const float*)d_in[14], (const float*)d_in[15], H1);
  k_conv2_both<<<dim3(9, 17, 2), b256, 0, stream>>>(H1,
      (const float*)d_in[8], (const float*)d_in[9],
      (const float*)d_in[16], (const float*)d_in[17], H2_0, H2_1);
  k_tc_both<<<dim3(32, 32, 2), b16, 0, stream>>>(H2_0, H2_1,
      (const float*)d_in[10], (const float*)d_in[11],
      (const float*)d_in[12], (const float*)d_in[13],
      (const float*)d_in[18], (const float*)d_in[19],
      (const float*)d_in[20], (const float*)d_in[21], A);

  // ccnt aliases dead-H1 space: zero only AFTER conv2 consumed H1
  hipMemsetAsync(ccnt, 0, 1024 * sizeof(int), stream);

  k_extract<<<dim3(1024, 5), b256, 0, stream>>>(A, gcol, gval, gcnt,
      crowT, cvalT, ccnt, DEGACC, D0a, F0a, D1a, F1a);

  k_spmm<<<dim3(1024, 2), b256, 0, stream>>>(gcol, gval, gcnt,
      D0a, F0a, D1a, F1a, M0, BT, D0b, F0b, D1b, F1b);

  k_spmm2<<<dim3(128, 4), b256, 0, stream>>>(BT, D1b, F1b, crowT, cvalT, ccnt,
                                             M1, DEGACC, DIAGV);
  k_fin<<<4, b256, 0, stream>>>(DEGACC, DIAGV, D1c, F1c);

  k_maxdeg<<<1024, b256, 0, stream>>>(M0, D0b, F0b, M1, D1c, F1c, AN, D2, F2);

  k_an_mm<64, true><<<256, dim3(64, 4), 0, stream>>>(AN, D2, F2, XW1, bias1, HB);
  k_mm_small<64, 32, false, false><<<128, dim3(32, 8), 0, stream>>>(HB, w2, nullptr, HW2);
  k_an_mm<32, false><<<128, dim3(32, 8), 0, stream>>>(AN, D2, F2, HW2, bias2, out);
}

// Round 11
// 369.138 us; speedup vs baseline: 1.1568x; 1.1568x over previous
//
#include <hip/hip_runtime.h>
#include <math.h>

#define N 1024
#define NN (N*N)
#define NE 32768

// ---------------- workspace layout (floats) ----------------
#define OFF_A    ((size_t)0)
#define OFF_H10  ((size_t)(5*NN))
#define OFF_M0   ((size_t)(5*NN))
#define OFF_CSR  ((size_t)(7*NN))
#define OFF_BT   ((size_t)(9*NN))
#define OFF_M1   ((size_t)(10*NN))
#define OFF_AN   ((size_t)(11*NN))
#define OFF_H20  ((size_t)(13*NN))
#define OFF_H21  (OFF_H20 + 264196)
#define OFF_SC   (OFF_H21 + 264196)
// scalar vectors (1024 each)
#define SC_D0a 0
#define SC_F0a 1024
#define SC_D1a 2048
#define SC_F1a 3072
#define SC_D0b 4096
#define SC_F0b 5120
#define SC_D1b 6144
#define SC_F1b 7168
#define SC_D1c 8192
#define SC_F1c 9216
#define SC_D2  10240
#define SC_F2  11264
#define SC_DEG 12288
#define SC_DGV 13312
#define OFF_XW1  (OFF_SC + 14336)
#define OFF_HB   (OFF_XW1 + 65536)
#define OFF_HW2  (OFF_HB + 65536)

#define CSR_STRIDE 96
#define CSRF (1024 * CSR_STRIDE)
#define CSC_MAXT 80

// ---------------- edge scatter ----------------
__global__ void k_scatter5(const int* __restrict__ e0, const int* __restrict__ e1,
                           const int* __restrict__ e2, const int* __restrict__ e3,
                           const int* __restrict__ e4, float* __restrict__ A) {
  int g = blockIdx.x * 256 + threadIdx.x;
  int seg = g >> 15;
  int k = g & 32767;
  const int* e = (seg == 0) ? e0 : (seg == 1) ? e1 : (seg == 2) ? e2 : (seg == 3) ? e3 : e4;
  atomicAdd(&A[(size_t)seg * NN + (size_t)e[k] * N + e[NE + k]], 1.0f);
}

// ---------------- conv1 (pad=1) + relu + maxpool2 (R8 proven version) ----------------
template<int L>
__device__ __forceinline__ void conv1_body(const float* __restrict__ A,
    const float* __restrict__ W, const float* __restrict__ Bn, float* __restrict__ out) {
  __shared__ float sIn[L][34][35];
  __shared__ float sW[16 * L * 9];
  __shared__ float sB[16];
  int tid = threadIdx.y * 16 + threadIdx.x;
  for (int i = tid; i < 16 * L * 9; i += 256) sW[i] = W[i];
  if (tid < 16) sB[tid] = Bn[tid];
  const int x0 = blockIdx.x * 32 - 1;
  const int y0 = blockIdx.y * 32 - 1;
  for (int idx = tid; idx < L * 34 * 34; idx += 256) {
    int l = idx / (34 * 34);
    int rem = idx - l * 34 * 34;
    int r = rem / 34, c = rem - r * 34;
    int iy = y0 + r, ix = x0 + c;
    sIn[l][r][c] = (iy >= 0 && iy < N && ix >= 0 && ix < N) ? A[(size_t)l * NN + (size_t)iy * N + ix] : 0.f;
  }
  __syncthreads();
  const int tx = threadIdx.x, ty = threadIdx.y;
  float p[L][4][4];
  #pragma unroll
  for (int l = 0; l < L; ++l)
    #pragma unroll
    for (int r = 0; r < 4; ++r)
      #pragma unroll
      for (int c = 0; c < 4; ++c)
        p[l][r][c] = sIn[l][2 * ty + r][2 * tx + c];
  const int ox = blockIdx.x * 16 + tx;
  const int oy = blockIdx.y * 16 + ty;
  for (int oc = 0; oc < 16; ++oc) {
    float wr[L * 9];
    #pragma unroll
    for (int t = 0; t < L * 9; ++t) wr[t] = sW[oc * L * 9 + t];
    float m = -1e30f;
    #pragma unroll
    for (int dy = 0; dy < 2; ++dy)
      #pragma unroll
      for (int dx = 0; dx < 2; ++dx) {
        float s = 0.f;
        #pragma unroll
        for (int l = 0; l < L; ++l)
          #pragma unroll
          for (int ky = 0; ky < 3; ++ky)
            #pragma unroll
            for (int kx = 0; kx < 3; ++kx)
              s = fmaf(p[l][dy + ky][dx + kx], wr[l * 9 + ky * 3 + kx], s);
        m = fmaxf(m, s);
      }
    out[(size_t)oc * 262144 + (size_t)oy * 512 + ox] = fmaxf(m + sB[oc], 0.f);
  }
}

__global__ __launch_bounds__(256) void k_conv1_both(const float* __restrict__ Ab,
    const float* __restrict__ W0, const float* __restrict__ b0,
    const float* __restrict__ W1, const float* __restrict__ b1, float* __restrict__ H1b) {
  if (blockIdx.z == 0) conv1_body<2>(Ab, W0, b0, H1b);
  else                 conv1_body<3>(Ab + 2 * NN, W1, b1, H1b + 4 * NN);
}

// ---------------- conv2 (pad=2)+relu+maxpool2: DIRECT, no LDS staging, no barriers ----------------
// 1 pooled px/thread, 4 ocs; patch read as 2x float2 per row per ic (L1-served reuse)
__global__ __launch_bounds__(256) void k_conv2_both(const float* __restrict__ H1b,
    const float* __restrict__ W0, const float* __restrict__ b0,
    const float* __restrict__ W1, const float* __restrict__ b1,
    float* __restrict__ H2_0, float* __restrict__ H2_1) {
  const int z = blockIdx.z;
  const float* in = H1b + (size_t)z * 4 * NN;   // 16 x 512 x 512
  const float* W  = z ? W1 : W0;
  const float* Bn = z ? b1 : b0;
  float* out = z ? H2_1 : H2_0;
  __shared__ float sW[4 * 16 * 9];
  __shared__ float sB[4];
  const int tid = threadIdx.x;
  for (int i = tid; i < 576; i += 256) sW[i] = W[i];
  if (tid < 4) sB[tid] = Bn[tid];
  __syncthreads();
  const int tx = tid & 15, ty = tid >> 4;
  const int ox = blockIdx.x * 16 + tx;
  const int oy = blockIdx.y * 16 + ty;
  if (ox >= 257 || oy >= 257) return;
  const int x0 = 2 * ox - 2;   // even -> float2 aligned; pair OOB is all-or-nothing
  const int y0 = 2 * oy - 2;
  const bool c0ok = (x0 >= 0);          // only ox==0 has x0=-2
  const bool c1ok = (x0 + 2 < 512);     // only ox==256 has x0+2=512
  float acc[4][2][2];
  #pragma unroll
  for (int oc = 0; oc < 4; ++oc)
    #pragma unroll
    for (int dy = 0; dy < 2; ++dy)
      #pragma unroll
      for (int dx = 0; dx < 2; ++dx) acc[oc][dy][dx] = 0.f;
  for (int ic = 0; ic < 16; ++ic) {
    const float* base = in + (size_t)ic * 262144;
    float p[4][4];
    #pragma unroll
    for (int r = 0; r < 4; ++r) {
      const int iy = y0 + r;
      const bool rowok = (iy >= 0 && iy < 512);
      float2 a = make_float2(0.f, 0.f), b = make_float2(0.f, 0.f);
      if (rowok) {
        const float* rp = base + (size_t)iy * 512;
        if (c0ok) a = *(const float2*)(rp + x0);
        if (c1ok) b = *(const float2*)(rp + x0 + 2);
      }
      p[r][0] = a.x; p[r][1] = a.y; p[r][2] = b.x; p[r][3] = b.y;
    }
    #pragma unroll
    for (int oc = 0; oc < 4; ++oc) {
      float wr[9];
      #pragma unroll
      for (int t = 0; t < 9; ++t) wr[t] = sW[oc * 144 + ic * 9 + t];
      #pragma unroll
      for (int ky = 0; ky < 3; ++ky)
        #pragma unroll
        for (int kx = 0; kx < 3; ++kx) {
          const float w = wr[ky * 3 + kx];
          #pragma unroll
          for (int dy = 0; dy < 2; ++dy)
            #pragma unroll
            for (int dx = 0; dx < 2; ++dx)
              acc[oc][dy][dx] = fmaf(p[dy + ky][dx + kx], w, acc[oc][dy][dx]);
        }
    }
  }
  #pragma unroll
  for (int oc = 0; oc < 4; ++oc) {
    float m = fmaxf(fmaxf(acc[oc][0][0], acc[oc][0][1]), fmaxf(acc[oc][1][0], acc[oc][1][1]));
    out[(size_t)oc * 66049 + (size_t)oy * 257 + ox] = fmaxf(m + sB[oc], 0.f);
  }
}

// ---------------- fused tconv1+relu + tconv2+sigmoid + attended (A *= att), both blocks ----------------
__global__ __launch_bounds__(256) void k_tc_both(
    const float* __restrict__ H2_0, const float* __restrict__ H2_1,
    const float* __restrict__ t1w0, const float* __restrict__ t1b0,
    const float* __restrict__ t2w0, const float* __restrict__ t2b0,
    const float* __restrict__ t1w1, const float* __restrict__ t1b1,
    const float* __restrict__ t2w1, const float* __restrict__ t2b1,
    float* __restrict__ Ab) {
  const int z = blockIdx.z;
  const int L = 2 + z;
  const float* in  = z ? H2_1 : H2_0;
  const float* W1p = z ? t1w1 : t1w0;
  const float* B1p = z ? t1b1 : t1b0;
  const float* W2p = z ? t2w1 : t2w0;
  const float* B2p = z ? t2b1 : t2b0;
  float* A = Ab + (size_t)z * 2 * NN;
  __shared__ float sW1[256], sB1[16], sW2[192], sB2[3];
  int tid = threadIdx.y * 16 + threadIdx.x;
  sW1[tid] = W1p[tid];
  if (tid < 16) sB1[tid] = B1p[tid];
  for (int i = tid; i < L * 64; i += 256) sW2[i] = W2p[i];
  if (tid < L) sB2[tid] = B2p[tid];
  __syncthreads();
  const int n = blockIdx.x * 16 + threadIdx.x;   // 0..511
  const int m = blockIdx.y * 16 + threadIdx.y;   // 0..511
  const int p = m >> 1, q = n >> 1;
  const int f1y = 1 - (m & 1), f1x = 1 - (n & 1);
  float vin[4];
  #pragma unroll
  for (int ci = 0; ci < 4; ++ci) vin[ci] = in[(size_t)ci * 66049 + (size_t)p * 257 + q];
  float v[16];
  #pragma unroll
  for (int c = 0; c < 16; ++c) {
    float s = sB1[c];
    #pragma unroll
    for (int ci = 0; ci < 4; ++ci)
      s = fmaf(vin[ci], sW1[c * 16 + ci * 4 + f1y * 2 + f1x], s);
    v[c] = fmaxf(s, 0.f);
  }
  for (int l = 0; l < L; ++l) {
    #pragma unroll
    for (int dy = 0; dy < 2; ++dy)
      #pragma unroll
      for (int dx = 0; dx < 2; ++dx) {
        float s = sB2[l];
        #pragma unroll
        for (int c = 0; c < 16; ++c)
          s = fmaf(v[c], sW2[l * 64 + c * 4 + (1 - dy) * 2 + (1 - dx)], s);
        float sg = 1.f / (1.f + expf(-s));
        size_t idx = (size_t)l * NN + (size_t)(2 * m + dy) * N + (2 * n + dx);
        A[idx] *= sg;
      }
  }
}

// ---------------- extract: CSR of y=0..3, entry-major CSC of y=4 (A12); deg of y=0,2 ----------------
__global__ __launch_bounds__(256) void k_extract(const float* __restrict__ Ab,
    int* __restrict__ gcol, float* __restrict__ gval, int* __restrict__ gcnt,
    int* __restrict__ crowT, float* __restrict__ cvalT, int* __restrict__ ccnt,
    float* __restrict__ DEGACC,
    float* __restrict__ D0a, float* __restrict__ F0a,
    float* __restrict__ D1a, float* __restrict__ F1a) {
  const int row = blockIdx.x;
  const int y = blockIdx.y;                 // 0:A00 1:A01 2:A10 3:A11 4:A12
  const float* base = Ab + (size_t)y * NN + (size_t)row * N;
  __shared__ int cnt;
  __shared__ float sdiag;
  __shared__ float red[4];
  if (threadIdx.x == 0) cnt = 0;
  __syncthreads();
  const int j4 = threadIdx.x;
  float4 v = ((const float4*)base)[j4];
  if (j4 == (row >> 2)) sdiag = ((const float*)&v)[row & 3];
  if (y == 4) {
    if (threadIdx.x == 0) DEGACC[row] = 0.f;
    #pragma unroll
    for (int t = 0; t < 4; ++t) {
      float x = ((const float*)&v)[t];
      if (x != 0.f) {
        int j = 4 * j4 + t;
        int p = atomicAdd(&ccnt[j], 1);
        if (p < CSC_MAXT) { crowT[p * 1024 + j] = row; cvalT[p * 1024 + j] = x; }
      }
    }
    return;
  }
  const size_t rb = ((size_t)y * 1024 + row) * CSR_STRIDE;
  #pragma unroll
  for (int t = 0; t < 4; ++t) {
    float x = ((const float*)&v)[t];
    if (x != 0.f) {
      int p = atomicAdd(&cnt, 1);
      if (p < CSR_STRIDE) { gcol[rb + p] = 4 * j4 + t; gval[rb + p] = x; }
    }
  }
  float s = v.x + v.y + v.z + v.w;
  #pragma unroll
  for (int o = 32; o > 0; o >>= 1) s += __shfl_down(s, o, 64);
  if ((threadIdx.x & 63) == 0) red[threadIdx.x >> 6] = s;
  __syncthreads();
  if (threadIdx.x == 0) {
    gcnt[(size_t)y * 1024 + row] = (cnt < CSR_STRIDE) ? cnt : CSR_STRIDE;
    if (y == 0 || y == 2) {
      float tot = red[0] + red[1] + red[2] + red[3];
      float fl = (sdiag == 0.f) ? 1.f : 0.f;
      float deg = tot + fl;
      float* D = (y == 0) ? D0a : D1a;
      float* F = (y == 0) ? F0a : F1a;
      D[row] = (deg > 0.f) ? (1.f / sqrtf(deg)) : 0.f;
      F[row] = fl;
    }
  }
}

// ---------------- hop-1 double-sparse SpMM ----------------
__global__ __launch_bounds__(256) void k_spmm(
    const int* __restrict__ gcol, const float* __restrict__ gval, const int* __restrict__ gcnt,
    const float* __restrict__ D0a, const float* __restrict__ F0a,
    const float* __restrict__ D1a, const float* __restrict__ F1a,
    float* __restrict__ M0, float* __restrict__ BT,
    float* __restrict__ D0b, float* __restrict__ F0b,
    float* __restrict__ D1b, float* __restrict__ F1b) {
  const int row = blockIdx.x;
  const int y = blockIdx.y;
  const int lm = y * 2, rm = y * 2 + 1;
  const float* Da = y ? D1a : D0a;
  const float* Fa = y ? F1a : F0a;
  __shared__ __align__(16) float acc[1024];
  __shared__ int lcol[112];
  __shared__ float lw[112];
  __shared__ int lrc[112];
  __shared__ int cl;
  __shared__ float red[4];
  __shared__ float sdiag;
  ((float4*)acc)[threadIdx.x] = make_float4(0.f, 0.f, 0.f, 0.f);
  const float di = Da[row];
  const int cnt_l = gcnt[(size_t)lm * 1024 + row];
  const size_t lb = ((size_t)lm * 1024 + row) * CSR_STRIDE;
  if (threadIdx.x < cnt_l) {
    int k = gcol[lb + threadIdx.x];
    lcol[threadIdx.x] = k;
    lw[threadIdx.x] = di * gval[lb + threadIdx.x] * Da[k];
    lrc[threadIdx.x] = gcnt[(size_t)rm * 1024 + k];
  }
  if (threadIdx.x == 0) {
    int c = cnt_l;
    if (Fa[row] != 0.f) {
      lcol[c] = row; lw[c] = di * di; lrc[c] = gcnt[(size_t)rm * 1024 + row]; ++c;
    }
    cl = c;
  }
  __syncthreads();
  const int sub = threadIdx.x >> 5, lane = threadIdx.x & 31;
  const int cle = cl;
  for (int e = sub; e < cle; e += 8) {
    const int k = lcol[e];
    const float w = lw[e];
    const int rc = lrc[e];
    const size_t rbv = ((size_t)rm * 1024 + k) * CSR_STRIDE;
    for (int t = lane; t < rc; t += 32)
      atomicAdd(&acc[gcol[rbv + t]], w * gval[rbv + t]);
  }
  __syncthreads();
  float4 o = ((const float4*)acc)[threadIdx.x];
  float* C = y ? BT : M0;
  ((float4*)(C + (size_t)row * N))[threadIdx.x] = o;
  if (threadIdx.x == (row >> 2)) sdiag = ((const float*)&o)[row & 3];
  float s = o.x + o.y + o.z + o.w;
  #pragma unroll
  for (int off = 32; off > 0; off >>= 1) s += __shfl_down(s, off, 64);
  if ((threadIdx.x & 63) == 0) red[threadIdx.x >> 6] = s;
  __syncthreads();
  if (threadIdx.x == 0) {
    float tot = red[0] + red[1] + red[2] + red[3];
    float fl = (sdiag == 0.f) ? 1.f : 0.f;
    float deg = tot + fl;
    float* D = y ? D1b : D0b;
    float* F = y ? F1b : F0b;
    D[row] = (deg > 0.f) ? (1.f / sqrtf(deg)) : 0.f;
    F[row] = fl;
  }
}

// ---------------- hop-2: 8 rows x 256 cols per block; CSC amortized over 8 rows ----------------
__global__ __launch_bounds__(256) void k_spmm2(const float* __restrict__ BT,
    const float* __restrict__ D1b, const float* __restrict__ F1b,
    const int* __restrict__ crowT, const float* __restrict__ cvalT, const int* __restrict__ ccnt,
    float* __restrict__ M1, float* __restrict__ DEGACC, float* __restrict__ DIAGV) {
  const int g0 = blockIdx.x << 3;
  const int j  = (blockIdx.y << 8) + threadIdx.x;
  __shared__ float bt[1024 * 9];
  __shared__ float wsum[4][8];
  const int tid = threadIdx.x;
  for (int kq = 0; kq < 4; ++kq) {
    const int k = (kq << 8) + tid;
    const float dv = D1b[k];
    #pragma unroll
    for (int row = 0; row < 8; ++row)
      bt[k * 9 + row] = BT[(size_t)(g0 + row) * N + k] * dv;
  }
  __syncthreads();
  if (tid < 8) {
    const int gr = g0 + tid;
    bt[gr * 9 + tid] += F1b[gr] * D1b[gr];
  }
  __syncthreads();
  int cn = ccnt[j];
  cn = min(cn, CSC_MAXT);
  float o[8];
  #pragma unroll
  for (int row = 0; row < 8; ++row) o[row] = 0.f;
  for (int t = 0; t < cn; ++t) {
    const int   r = crowT[t * 1024 + j];
    const float v = cvalT[t * 1024 + j];
    const int rb = r * 9;
    #pragma unroll
    for (int row = 0; row < 8; ++row)
      o[row] = fmaf(bt[rb + row], v, o[row]);
  }
  #pragma unroll
  for (int row = 0; row < 8; ++row) o[row] *= D1b[g0 + row];
  #pragma unroll
  for (int row = 0; row < 8; ++row)
    M1[(size_t)(g0 + row) * N + j] = o[row];
  if ((unsigned)(j - g0) < 8u) DIAGV[j] = o[j - g0];
  #pragma unroll
  for (int row = 0; row < 8; ++row) {
    float s = o[row];
    #pragma unroll
    for (int off = 32; off > 0; off >>= 1) s += __shfl_down(s, off, 64);
    if ((tid & 63) == 0) wsum[tid >> 6][row] = s;
  }
  __syncthreads();
  if (tid < 8) {
    float p = wsum[0][tid] + wsum[1][tid] + wsum[2][tid] + wsum[3][tid];
    atomicAdd(&DEGACC[g0 + tid], p);
  }
}

// ---------------- finish deg of M1 ----------------
__global__ void k_fin(const float* __restrict__ DEGACC, const float* __restrict__ DIAGV,
                      float* __restrict__ D1c, float* __restrict__ F1c) {
  const int row = blockIdx.x * 256 + threadIdx.x;
  const float fl = (DIAGV[row] == 0.f) ? 1.f : 0.f;
  const float deg = DEGACC[row] + fl;
  D1c[row] = (deg > 0.f) ? (1.f / sqrtf(deg)) : 0.f;
  F1c[row] = fl;
}

// ---------------- fused max(scale0(M0), scale1(M1)) + deg of result ----------------
__global__ __launch_bounds__(256) void k_maxdeg(const float* __restrict__ M0,
    const float* __restrict__ d0, const float* __restrict__ f0,
    const float* __restrict__ M1, const float* __restrict__ d1, const float* __restrict__ f1,
    float* __restrict__ Aout, float* __restrict__ dinv2, float* __restrict__ dflg2) {
  const int row = blockIdx.x;
  const int j4 = threadIdx.x;
  const float r0 = d0[row], r1 = d1[row];
  const float fl0 = f0[row], fl1 = f1[row];
  float4 a = ((const float4*)(M0 + (size_t)row * N))[j4];
  float4 b = ((const float4*)(M1 + (size_t)row * N))[j4];
  const float4 c0 = ((const float4*)d0)[j4];
  const float4 c1 = ((const float4*)d1)[j4];
  int d = row - 4 * j4;
  if ((unsigned)d < 4u) { ((float*)&a)[d] += fl0; ((float*)&b)[d] += fl1; }
  float4 o;
  o.x = fmaxf(a.x * r0 * c0.x, b.x * r1 * c1.x);
  o.y = fmaxf(a.y * r0 * c0.y, b.y * r1 * c1.y);
  o.z = fmaxf(a.z * r0 * c0.z, b.z * r1 * c1.z);
  o.w = fmaxf(a.w * r0 * c0.w, b.w * r1 * c1.w);
  ((float4*)(Aout + (size_t)row * N))[j4] = o;
  __shared__ float sdiag;
  if ((unsigned)d < 4u) sdiag = ((float*)&o)[d];
  float s = o.x + o.y + o.z + o.w;
  #pragma unroll
  for (int off = 32; off > 0; off >>= 1) s += __shfl_down(s, off, 64);
  __shared__ float red[4];
  if ((threadIdx.x & 63) == 0) red[threadIdx.x >> 6] = s;
  __syncthreads();
  if (threadIdx.x == 0) {
    float tot = red[0] + red[1] + red[2] + red[3];
    float fl = (sdiag == 0.0f) ? 1.0f : 0.0f;
    float deg = tot + fl;
    dinv2[row] = (deg > 0.0f) ? (1.0f / sqrtf(deg)) : 0.0f;
    dflg2[row] = fl;
  }
}

// ---------------- skinny matmul ----------------
template<int K, int NCOL, bool BIAS, bool RELU>
__global__ void k_mm_small(const float* __restrict__ A, const float* __restrict__ B,
                           const float* __restrict__ bias, float* __restrict__ out) {
  const int j = threadIdx.x;
  const int i = blockIdx.x * blockDim.y + threadIdx.y;
  const float* ar = A + (size_t)i * K;
  float acc = 0.f;
  #pragma unroll 8
  for (int k = 0; k < K; ++k) acc = fmaf(ar[k], B[(size_t)k * NCOL + j], acc);
  if (BIAS) acc += bias[j];
  if (RELU) acc = fmaxf(acc, 0.f);
  out[(size_t)i * NCOL + j] = acc;
}

// ---------------- skinny matmul with fused An normalization ----------------
template<int NCOL, bool RELU>
__global__ void k_an_mm(const float* __restrict__ BT, const float* __restrict__ dinv,
                        const float* __restrict__ dflg, const float* __restrict__ Bm,
                        const float* __restrict__ bias, float* __restrict__ out) {
  const int j = threadIdx.x;
  const int i = blockIdx.x * blockDim.y + threadIdx.y;
  const float di = dinv[i];
  const float* ar = BT + (size_t)i * N;
  float acc = 0.f;
  for (int k = 0; k < N; k += 4) {
    float4 a4 = *(const float4*)&ar[k];
    float4 d4 = *(const float4*)&dinv[k];
    acc = fmaf(a4.x * d4.x, Bm[(size_t)(k + 0) * NCOL + j], acc);
    acc = fmaf(a4.y * d4.y, Bm[(size_t)(k + 1) * NCOL + j], acc);
    acc = fmaf(a4.z * d4.z, Bm[(size_t)(k + 2) * NCOL + j], acc);
    acc = fmaf(a4.w * d4.w, Bm[(size_t)(k + 3) * NCOL + j], acc);
  }
  acc = fmaf(dflg[i] * dinv[i], Bm[(size_t)i * NCOL + j], acc);
  acc = fmaf(di, acc, bias[j]);
  if (RELU) acc = fmaxf(acc, 0.f);
  out[(size_t)i * NCOL + j] = acc;
}

// ---------------- launcher ----------------
extern "C" void kernel_launch(void* const* d_in, const int* in_sizes, int n_in,
                              void* d_out, int out_size, void* d_ws, size_t ws_size,
                              hipStream_t stream) {
  const float* x     = (const float*)d_in[0];
  const float* w1    = (const float*)d_in[22];
  const float* bias1 = (const float*)d_in[23];
  const float* w2    = (const float*)d_in[24];
  const float* bias2 = (const float*)d_in[25];
  float* out = (float*)d_out;
  float* ws  = (float*)d_ws;

  float* A    = ws + OFF_A;
  float* H1   = ws + OFF_H10;
  float* M0   = ws + OFF_M0;
  float* BT   = ws + OFF_BT;
  float* M1   = ws + OFF_M1;
  float* AN   = ws + OFF_AN;
  float* H2_0 = ws + OFF_H20;
  float* H2_1 = ws + OFF_H21;
  int*   gcol  = (int*)(ws + OFF_CSR);
  float* gval  = ws + OFF_CSR + (size_t)4 * CSRF;
  int*   gcnt  = (int*)(ws + OFF_CSR + (size_t)8 * CSRF);
  int*   crowT = (int*)(ws + OFF_CSR + (size_t)8 * CSRF + 4096);
  float* cvalT = ws + OFF_CSR + (size_t)8 * CSRF + 4096 + CSC_MAXT * 1024;
  int*   ccnt  = (int*)(ws + OFF_CSR + (size_t)8 * CSRF + 4096 + (size_t)2 * CSC_MAXT * 1024);
  float* SC   = ws + OFF_SC;
  float *D0a = SC + SC_D0a, *F0a = SC + SC_F0a, *D1a = SC + SC_D1a, *F1a = SC + SC_F1a;
  float *D0b = SC + SC_D0b, *F0b = SC + SC_F0b, *D1b = SC + SC_D1b, *F1b = SC + SC_F1b;
  float *D1c = SC + SC_D1c, *F1c = SC + SC_F1c, *D2 = SC + SC_D2, *F2 = SC + SC_F2;
  float *DEGACC = SC + SC_DEG, *DIAGV = SC + SC_DGV;
  float* XW1 = ws + OFF_XW1;
  float* HB  = ws + OFF_HB;
  float* HW2 = ws + OFF_HW2;

  hipMemsetAsync(A, 0, (size_t)5 * NN * sizeof(float), stream);

  dim3 b256(256), b16(16, 16);
  // independent: x @ w1
  k_mm_small<128, 64, false, false><<<256, dim3(64, 4), 0, stream>>>(x, w1, nullptr, XW1);

  k_scatter5<<<640, b256, 0, stream>>>((const int*)d_in[1], (const int*)d_in[2],
                                       (const int*)d_in[3], (const int*)d_in[4],
                                       (const int*)d_in[5], A);

  // attention encoders
  k_conv1_both<<<dim3(32, 32, 2), b16, 0, stream>>>(A,
      (const float*)d_in[6], (const float*)d_in[7],
      (const float*)d_in[14], (const float*)d_in[15], H1);
  k_conv2_both<<<dim3(17, 17, 2), b256, 0, stream>>>(H1,
      (const float*)d_in[8], (const float*)d_in[9],
      (const float*)d_in[16], (const float*)d_in[17], H2_0, H2_1);
  k_tc_both<<<dim3(32, 32, 2), b16, 0, stream>>>(H2_0, H2_1,
      (const float*)d_in[10], (const float*)d_in[11],
      (const float*)d_in[12], (const float*)d_in[13],
      (const float*)d_in[18], (const float*)d_in[19],
      (const float*)d_in[20], (const float*)d_in[21], A);

  // ccnt aliases dead-H1 space: zero only AFTER conv2 consumed H1
  hipMemsetAsync(ccnt, 0, 1024 * sizeof(int), stream);

  k_extract<<<dim3(1024, 5), b256, 0, stream>>>(A, gcol, gval, gcnt,
      crowT, cvalT, ccnt, DEGACC, D0a, F0a, D1a, F1a);

  k_spmm<<<dim3(1024, 2), b256, 0, stream>>>(gcol, gval, gcnt,
      D0a, F0a, D1a, F1a, M0, BT, D0b, F0b, D1b, F1b);

  k_spmm2<<<dim3(128, 4), b256, 0, stream>>>(BT, D1b, F1b, crowT, cvalT, ccnt,
                                             M1, DEGACC, DIAGV);
  k_fin<<<4, b256, 0, stream>>>(DEGACC, DIAGV, D1c, F1c);

  k_maxdeg<<<1024, b256, 0, stream>>>(M0, D0b, F0b, M1, D1c, F1c, AN, D2, F2);

  k_an_mm<64, true><<<256, dim3(64, 4), 0, stream>>>(AN, D2, F2, XW1, bias1, HB);
  k_mm_small<64, 32, false, false><<<128, dim3(32, 8), 0, stream>>>(HB, w2, nullptr, HW2);
  k_an_mm<32, false><<<128, dim3(32, 8), 0, stream>>>(AN, D2, F2, HW2, bias2, out);
}

// Round 13
// 342.975 us; speedup vs baseline: 1.2451x; 1.0763x over previous
//
#include <hip/hip_runtime.h>
#include <math.h>

#define N 1024
#define NN (N*N)
#define NE 32768

// ---------------- workspace layout (floats) ----------------
#define OFF_A    ((size_t)0)
#define OFF_H10  ((size_t)(5*NN))
#define OFF_M0   ((size_t)(5*NN))
#define OFF_CSR  ((size_t)(7*NN))          // gcol/gval/crowT/cvalT (dead-H1 space, written by tc_emit)
#define OFF_BT   ((size_t)(9*NN))
#define OFF_M1   ((size_t)(10*NN))
#define OFF_AN   ((size_t)(11*NN))
#define OFF_H20  ((size_t)(13*NN))
#define OFF_H21  (OFF_H20 + 264196)
#define OFF_SC   (OFF_H21 + 264196)
// SC scalar region (floats). [SC_ZERO, SC_ZERO+10240) zeroed by conv1 block0.
#define SC_D0a   0
#define SC_F0a   1024
#define SC_D1a   2048
#define SC_F1a   3072
#define SC_D0b   4096
#define SC_F0b   5120
#define SC_D1b   6144
#define SC_F1b   7168
#define SC_D2    8192
#define SC_F2    9216
#define SC_ZERO  10240
#define SC_DEG   10240      /* DEGACC (spmm2) 1024 */
#define SC_GCNT  11264      /* 4096 ints */
#define SC_CCNT  15360      /* 1024 ints */
#define SC_DEGA  16384      /* row-sum acc for A00/A10, 2048 */
#define SC_DIAGA 18432      /* diag of A00/A10, 2048 */
#define SC_DGV   20480      /* DIAGV (spmm2, densely written) 1024 */
#define SC_END   21504
#define OFF_XW1  (OFF_SC + SC_END)
#define OFF_HW2  (OFF_XW1 + 65536)

#define CSR_STRIDE 96
#define CSRF (1024 * CSR_STRIDE)
#define CSC_MAXT 80

// ---------------- edge scatter ----------------
__global__ void k_scatter5(const int* __restrict__ e0, const int* __restrict__ e1,
                           const int* __restrict__ e2, const int* __restrict__ e3,
                           const int* __restrict__ e4, float* __restrict__ A) {
  int g = blockIdx.x * 256 + threadIdx.x;
  int seg = g >> 15;
  int k = g & 32767;
  const int* e = (seg == 0) ? e0 : (seg == 1) ? e1 : (seg == 2) ? e2 : (seg == 3) ? e3 : e4;
  atomicAdd(&A[(size_t)seg * NN + (size_t)e[k] * N + e[NE + k]], 1.0f);
}

// ---------------- conv1 (pad=1) + relu + maxpool2 (+ counter zeroing in block 0) ----------------
template<int L>
__device__ __forceinline__ void conv1_body(const float* __restrict__ A,
    const float* __restrict__ W, const float* __restrict__ Bn, float* __restrict__ out) {
  __shared__ float sIn[L][34][35];
  __shared__ float sW[16 * L * 9];
  __shared__ float sB[16];
  int tid = threadIdx.y * 16 + threadIdx.x;
  for (int i = tid; i < 16 * L * 9; i += 256) sW[i] = W[i];
  if (tid < 16) sB[tid] = Bn[tid];
  const int x0 = blockIdx.x * 32 - 1;
  const int y0 = blockIdx.y * 32 - 1;
  for (int idx = tid; idx < L * 34 * 34; idx += 256) {
    int l = idx / (34 * 34);
    int rem = idx - l * 34 * 34;
    int r = rem / 34, c = rem - r * 34;
    int iy = y0 + r, ix = x0 + c;
    sIn[l][r][c] = (iy >= 0 && iy < N && ix >= 0 && ix < N) ? A[(size_t)l * NN + (size_t)iy * N + ix] : 0.f;
  }
  __syncthreads();
  const int tx = threadIdx.x, ty = threadIdx.y;
  float p[L][4][4];
  #pragma unroll
  for (int l = 0; l < L; ++l)
    #pragma unroll
    for (int r = 0; r < 4; ++r)
      #pragma unroll
      for (int c = 0; c < 4; ++c)
        p[l][r][c] = sIn[l][2 * ty + r][2 * tx + c];
  const int ox = blockIdx.x * 16 + tx;
  const int oy = blockIdx.y * 16 + ty;
  for (int oc = 0; oc < 16; ++oc) {
    float wr[L * 9];
    #pragma unroll
    for (int t = 0; t < L * 9; ++t) wr[t] = sW[oc * L * 9 + t];
    float m = -1e30f;
    #pragma unroll
    for (int dy = 0; dy < 2; ++dy)
      #pragma unroll
      for (int dx = 0; dx < 2; ++dx) {
        float s = 0.f;
        #pragma unroll
        for (int l = 0; l < L; ++l)
          #pragma unroll
          for (int ky = 0; ky < 3; ++ky)
            #pragma unroll
            for (int kx = 0; kx < 3; ++kx)
              s = fmaf(p[l][dy + ky][dx + kx], wr[l * 9 + ky * 3 + kx], s);
        m = fmaxf(m, s);
      }
    out[(size_t)oc * 262144 + (size_t)oy * 512 + ox] = fmaxf(m + sB[oc], 0.f);
  }
}

__global__ __launch_bounds__(256) void k_conv1_both(const float* __restrict__ Ab,
    const float* __restrict__ W0, const float* __restrict__ b0,
    const float* __restrict__ W1, const float* __restrict__ b1,
    float* __restrict__ H1b, float* __restrict__ ZC) {
  // block (0,0,0): zero counters (gcnt/ccnt/DEGA/DIAGA/DEGACC) used by tc_emit/spmm2
  if (blockIdx.x == 0 && blockIdx.y == 0 && blockIdx.z == 0) {
    int tid = threadIdx.y * 16 + threadIdx.x;
    for (int i = tid; i < 10240; i += 256) ZC[i] = 0.f;
  }
  if (blockIdx.z == 0) conv1_body<2>(Ab, W0, b0, H1b);
  else                 conv1_body<3>(Ab + 2 * NN, W1, b1, H1b + 4 * NN);
}

// ---------------- conv2 (pad=2)+relu+maxpool2: DIRECT (R11 proven) ----------------
__global__ __launch_bounds__(256) void k_conv2_both(const float* __restrict__ H1b,
    const float* __restrict__ W0, const float* __restrict__ b0,
    const float* __restrict__ W1, const float* __restrict__ b1,
    float* __restrict__ H2_0, float* __restrict__ H2_1) {
  const int z = blockIdx.z;
  const float* in = H1b + (size_t)z * 4 * NN;
  const float* W  = z ? W1 : W0;
  const float* Bn = z ? b1 : b0;
  float* out = z ? H2_1 : H2_0;
  __shared__ float sW[4 * 16 * 9];
  __shared__ float sB[4];
  const int tid = threadIdx.x;
  for (int i = tid; i < 576; i += 256) sW[i] = W[i];
  if (tid < 4) sB[tid] = Bn[tid];
  __syncthreads();
  const int tx = tid & 15, ty = tid >> 4;
  const int ox = blockIdx.x * 16 + tx;
  const int oy = blockIdx.y * 16 + ty;
  if (ox >= 257 || oy >= 257) return;
  const int x0 = 2 * ox - 2;
  const int y0 = 2 * oy - 2;
  const bool c0ok = (x0 >= 0);
  const bool c1ok = (x0 + 2 < 512);
  float acc[4][2][2];
  #pragma unroll
  for (int oc = 0; oc < 4; ++oc)
    #pragma unroll
    for (int dy = 0; dy < 2; ++dy)
      #pragma unroll
      for (int dx = 0; dx < 2; ++dx) acc[oc][dy][dx] = 0.f;
  for (int ic = 0; ic < 16; ++ic) {
    const float* base = in + (size_t)ic * 262144;
    float p[4][4];
    #pragma unroll
    for (int r = 0; r < 4; ++r) {
      const int iy = y0 + r;
      const bool rowok = (iy >= 0 && iy < 512);
      float2 a = make_float2(0.f, 0.f), b = make_float2(0.f, 0.f);
      if (rowok) {
        const float* rp = base + (size_t)iy * 512;
        if (c0ok) a = *(const float2*)(rp + x0);
        if (c1ok) b = *(const float2*)(rp + x0 + 2);
      }
      p[r][0] = a.x; p[r][1] = a.y; p[r][2] = b.x; p[r][3] = b.y;
    }
    #pragma unroll
    for (int oc = 0; oc < 4; ++oc) {
      float wr[9];
      #pragma unroll
      for (int t = 0; t < 9; ++t) wr[t] = sW[oc * 144 + ic * 9 + t];
      #pragma unroll
      for (int ky = 0; ky < 3; ++ky)
        #pragma unroll
        for (int kx = 0; kx < 3; ++kx) {
          const float w = wr[ky * 3 + kx];
          #pragma unroll
          for (int dy = 0; dy < 2; ++dy)
            #pragma unroll
            for (int dx = 0; dx < 2; ++dx)
              acc[oc][dy][dx] = fmaf(p[dy + ky][dx + kx], w, acc[oc][dy][dx]);
        }
    }
  }
  #pragma unroll
  for (int oc = 0; oc < 4; ++oc) {
    float m = fmaxf(fmaxf(acc[oc][0][0], acc[oc][0][1]), fmaxf(acc[oc][1][0], acc[oc][1][1]));
    out[(size_t)oc * 66049 + (size_t)oy * 257 + ox] = fmaxf(m + sB[oc], 0.f);
  }
}

// ---------------- tconv1+tconv2+sigmoid + DIRECT sparse emit (no dense attended write) ----------------
// v = A[mat][grow][gc] * sigmoid(...); emit CSR (mat 0-3) / CSC (mat 4); DEG/DIAG for mats 0,2 ONLY
__global__ __launch_bounds__(256) void k_tc_emit(
    const float* __restrict__ H2_0, const float* __restrict__ H2_1,
    const float* __restrict__ t1w0, const float* __restrict__ t1b0,
    const float* __restrict__ t2w0, const float* __restrict__ t2b0,
    const float* __restrict__ t1w1, const float* __restrict__ t1b1,
    const float* __restrict__ t2w1, const float* __restrict__ t2b1,
    const float* __restrict__ Ab,
    int* __restrict__ gcolA, float* __restrict__ gvalA, int* __restrict__ gcntA,
    int* __restrict__ crowT, float* __restrict__ cvalT, int* __restrict__ ccnt,
    float* __restrict__ DEGA, float* __restrict__ DIAGA) {
  const int z = blockIdx.z;
  const int L = 2 + z;
  const float* in  = z ? H2_1 : H2_0;
  const float* W1p = z ? t1w1 : t1w0;
  const float* B1p = z ? t1b1 : t1b0;
  const float* W2p = z ? t2w1 : t2w0;
  const float* B2p = z ? t2b1 : t2b0;
  __shared__ float sW1[256], sB1[16], sW2[192], sB2[3];
  int tid = threadIdx.y * 16 + threadIdx.x;
  sW1[tid] = W1p[tid];
  if (tid < 16) sB1[tid] = B1p[tid];
  for (int i = tid; i < L * 64; i += 256) sW2[i] = W2p[i];
  if (tid < L) sB2[tid] = B2p[tid];
  __syncthreads();
  const int n = blockIdx.x * 16 + threadIdx.x;   // 0..511
  const int m = blockIdx.y * 16 + threadIdx.y;   // 0..511
  const int p = m >> 1, q = n >> 1;
  const int f1y = 1 - (m & 1), f1x = 1 - (n & 1);
  float vin[4];
  #pragma unroll
  for (int ci = 0; ci < 4; ++ci) vin[ci] = in[(size_t)ci * 66049 + (size_t)p * 257 + q];
  float v16[16];
  #pragma unroll
  for (int c = 0; c < 16; ++c) {
    float s = sB1[c];
    #pragma unroll
    for (int ci = 0; ci < 4; ++ci)
      s = fmaf(vin[ci], sW1[c * 16 + ci * 4 + f1y * 2 + f1x], s);
    v16[c] = fmaxf(s, 0.f);
  }
  for (int l = 0; l < L; ++l) {
    const int mat = z * 2 + l;
    #pragma unroll
    for (int dy = 0; dy < 2; ++dy)
      #pragma unroll
      for (int dx = 0; dx < 2; ++dx) {
        float s = sB2[l];
        #pragma unroll
        for (int c = 0; c < 16; ++c)
          s = fmaf(v16[c], sW2[l * 64 + c * 4 + (1 - dy) * 2 + (1 - dx)], s);
        const float sg = 1.f / (1.f + expf(-s));
        const int grow = 2 * m + dy, gc = 2 * n + dx;
        const float av = Ab[(size_t)mat * NN + (size_t)grow * N + gc];
        const float v = av * sg;
        if (v != 0.f) {
          if (mat == 4) {
            int pp = atomicAdd(&ccnt[gc], 1);
            if (pp < CSC_MAXT) { crowT[pp * 1024 + gc] = grow; cvalT[pp * 1024 + gc] = v; }
          } else {
            int pp = atomicAdd(&gcntA[mat * 1024 + grow], 1);
            if (pp < CSR_STRIDE) {
              size_t rb = ((size_t)mat * 1024 + grow) * CSR_STRIDE;
              gcolA[rb + pp] = gc; gvalA[rb + pp] = v;
            }
          }
          if (mat == 0 || mat == 2) {     // left matrices ONLY (R12 bug: mat==4 also passed (mat&1)==0)
            atomicAdd(&DEGA[(mat >> 1) * 1024 + grow], v);
            if (grow == gc) DIAGA[(mat >> 1) * 1024 + grow] = v;
          }
        }
      }
  }
}

// ---------------- finish degs of A00/A10 ----------------
__global__ void k_finA(const float* __restrict__ DEGA, const float* __restrict__ DIAGA,
    float* __restrict__ D0a, float* __restrict__ F0a,
    float* __restrict__ D1a, float* __restrict__ F1a) {
  const int i = blockIdx.x * 256 + threadIdx.x;   // 0..2047
  const int which = i >> 10, row = i & 1023;
  const float fl = (DIAGA[i] == 0.f) ? 1.f : 0.f;
  const float deg = DEGA[i] + fl;
  const float d = (deg > 0.f) ? (1.f / sqrtf(deg)) : 0.f;
  if (which == 0) { D0a[row] = d; F0a[row] = fl; }
  else            { D1a[row] = d; F1a[row] = fl; }
}

// ---------------- hop-1 double-sparse SpMM ----------------
__global__ __launch_bounds__(256) void k_spmm(
    const int* __restrict__ gcol, const float* __restrict__ gval, const int* __restrict__ gcnt,
    const float* __restrict__ D0a, const float* __restrict__ F0a,
    const float* __restrict__ D1a, const float* __restrict__ F1a,
    float* __restrict__ M0, float* __restrict__ BT,
    float* __restrict__ D0b, float* __restrict__ F0b,
    float* __restrict__ D1b, float* __restrict__ F1b) {
  const int row = blockIdx.x;
  const int y = blockIdx.y;
  const int lm = y * 2, rm = y * 2 + 1;
  const float* Da = y ? D1a : D0a;
  const float* Fa = y ? F1a : F0a;
  __shared__ __align__(16) float acc[1024];
  __shared__ int lcol[112];
  __shared__ float lw[112];
  __shared__ int lrc[112];
  __shared__ int cl;
  __shared__ float red[4];
  __shared__ float sdiag;
  ((float4*)acc)[threadIdx.x] = make_float4(0.f, 0.f, 0.f, 0.f);
  const float di = Da[row];
  const int cnt_l = min(gcnt[(size_t)lm * 1024 + row], CSR_STRIDE);
  const size_t lb = ((size_t)lm * 1024 + row) * CSR_STRIDE;
  if (threadIdx.x < cnt_l) {
    int k = gcol[lb + threadIdx.x];
    lcol[threadIdx.x] = k;
    lw[threadIdx.x] = di * gval[lb + threadIdx.x] * Da[k];
    lrc[threadIdx.x] = min(gcnt[(size_t)rm * 1024 + k], CSR_STRIDE);
  }
  if (threadIdx.x == 0) {
    int c = cnt_l;
    if (Fa[row] != 0.f) {
      lcol[c] = row; lw[c] = di * di;
      lrc[c] = min(gcnt[(size_t)rm * 1024 + row], CSR_STRIDE); ++c;
    }
    cl = c;
  }
  __syncthreads();
  const int sub = threadIdx.x >> 5, lane = threadIdx.x & 31;
  const int cle = cl;
  for (int e = sub; e < cle; e += 8) {
    const int k = lcol[e];
    const float w = lw[e];
    const int rc = lrc[e];
    const size_t rbv = ((size_t)rm * 1024 + k) * CSR_STRIDE;
    for (int t = lane; t < rc; t += 32)
      atomicAdd(&acc[gcol[rbv + t]], w * gval[rbv + t]);
  }
  __syncthreads();
  float4 o = ((const float4*)acc)[threadIdx.x];
  float* C = y ? BT : M0;
  ((float4*)(C + (size_t)row * N))[threadIdx.x] = o;
  if (threadIdx.x == (row >> 2)) sdiag = ((const float*)&o)[row & 3];
  float s = o.x + o.y + o.z + o.w;
  #pragma unroll
  for (int off = 32; off > 0; off >>= 1) s += __shfl_down(s, off, 64);
  if ((threadIdx.x & 63) == 0) red[threadIdx.x >> 6] = s;
  __syncthreads();
  if (threadIdx.x == 0) {
    float tot = red[0] + red[1] + red[2] + red[3];
    float fl = (sdiag == 0.f) ? 1.f : 0.f;
    float deg = tot + fl;
    float* D = y ? D1b : D0b;
    float* F = y ? F1b : F0b;
    D[row] = (deg > 0.f) ? (1.f / sqrtf(deg)) : 0.f;
    F[row] = fl;
  }
}

// ---------------- hop-2: 8 rows x 256 cols per block; CSC amortized ----------------
__global__ __launch_bounds__(256) void k_spmm2(const float* __restrict__ BT,
    const float* __restrict__ D1b, const float* __restrict__ F1b,
    const int* __restrict__ crowT, const float* __restrict__ cvalT, const int* __restrict__ ccnt,
    float* __restrict__ M1, float* __restrict__ DEGACC, float* __restrict__ DIAGV) {
  const int g0 = blockIdx.x << 3;
  const int j  = (blockIdx.y << 8) + threadIdx.x;
  __shared__ float bt[1024 * 9];
  __shared__ float wsum[4][8];
  const int tid = threadIdx.x;
  for (int kq = 0; kq < 4; ++kq) {
    const int k = (kq << 8) + tid;
    const float dv = D1b[k];
    #pragma unroll
    for (int row = 0; row < 8; ++row)
      bt[k * 9 + row] = BT[(size_t)(g0 + row) * N + k] * dv;
  }
  __syncthreads();
  if (tid < 8) {
    const int gr = g0 + tid;
    bt[gr * 9 + tid] += F1b[gr] * D1b[gr];
  }
  __syncthreads();
  int cn = ccnt[j];
  cn = min(cn, CSC_MAXT);
  float o[8];
  #pragma unroll
  for (int row = 0; row < 8; ++row) o[row] = 0.f;
  for (int t = 0; t < cn; ++t) {
    const int   r = crowT[t * 1024 + j];
    const float v = cvalT[t * 1024 + j];
    const int rb = r * 9;
    #pragma unroll
    for (int row = 0; row < 8; ++row)
      o[row] = fmaf(bt[rb + row], v, o[row]);
  }
  #pragma unroll
  for (int row = 0; row < 8; ++row) o[row] *= D1b[g0 + row];
  #pragma unroll
  for (int row = 0; row < 8; ++row)
    M1[(size_t)(g0 + row) * N + j] = o[row];
  if ((unsigned)(j - g0) < 8u) DIAGV[j] = o[j - g0];
  #pragma unroll
  for (int row = 0; row < 8; ++row) {
    float s = o[row];
    #pragma unroll
    for (int off = 32; off > 0; off >>= 1) s += __shfl_down(s, off, 64);
    if ((tid & 63) == 0) wsum[tid >> 6][row] = s;
  }
  __syncthreads();
  if (tid < 8) {
    float p = wsum[0][tid] + wsum[1][tid] + wsum[2][tid] + wsum[3][tid];
    atomicAdd(&DEGACC[g0 + tid], p);
  }
}

// ---------------- fused max(scale(M0), scale(M1)) + inline M1-deg + deg of result ----------------
__global__ __launch_bounds__(256) void k_maxdeg(const float* __restrict__ M0,
    const float* __restrict__ d0, const float* __restrict__ f0,
    const float* __restrict__ M1,
    const float* __restrict__ DEGACC, const float* __restrict__ DIAGV,
    float* __restrict__ Aout, float* __restrict__ dinv2, float* __restrict__ dflg2) {
  const int row = blockIdx.x;
  const int j4 = threadIdx.x;
  const float r0 = d0[row], fl0 = f0[row];
  const float flr = (DIAGV[row] == 0.f) ? 1.f : 0.f;
  const float degr = DEGACC[row] + flr;
  const float r1 = (degr > 0.f) ? (1.f / sqrtf(degr)) : 0.f;
  const float fl1 = flr;
  float4 a = ((const float4*)(M0 + (size_t)row * N))[j4];
  float4 b = ((const float4*)(M1 + (size_t)row * N))[j4];
  const float4 c0 = ((const float4*)d0)[j4];
  const float4 da = ((const float4*)DEGACC)[j4];
  const float4 gv = ((const float4*)DIAGV)[j4];
  float4 c1;
  {
    float fx = (gv.x == 0.f) ? 1.f : 0.f, dx_ = da.x + fx;
    float fy = (gv.y == 0.f) ? 1.f : 0.f, dy_ = da.y + fy;
    float fz = (gv.z == 0.f) ? 1.f : 0.f, dz_ = da.z + fz;
    float fw = (gv.w == 0.f) ? 1.f : 0.f, dw_ = da.w + fw;
    c1.x = (dx_ > 0.f) ? (1.f / sqrtf(dx_)) : 0.f;
    c1.y = (dy_ > 0.f) ? (1.f / sqrtf(dy_)) : 0.f;
    c1.z = (dz_ > 0.f) ? (1.f / sqrtf(dz_)) : 0.f;
    c1.w = (dw_ > 0.f) ? (1.f / sqrtf(dw_)) : 0.f;
  }
  int d = row - 4 * j4;
  if ((unsigned)d < 4u) { ((float*)&a)[d] += fl0; ((float*)&b)[d] += fl1; }
  float4 o;
  o.x = fmaxf(a.x * r0 * c0.x, b.x * r1 * c1.x);
  o.y = fmaxf(a.y * r0 * c0.y, b.y * r1 * c1.y);
  o.z = fmaxf(a.z * r0 * c0.z, b.z * r1 * c1.z);
  o.w = fmaxf(a.w * r0 * c0.w, b.w * r1 * c1.w);
  ((float4*)(Aout + (size_t)row * N))[j4] = o;
  __shared__ float sdiag;
  if ((unsigned)d < 4u) sdiag = ((float*)&o)[d];
  float s = o.x + o.y + o.z + o.w;
  #pragma unroll
  for (int off = 32; off > 0; off >>= 1) s += __shfl_down(s, off, 64);
  __shared__ float red[4];
  if ((threadIdx.x & 63) == 0) red[threadIdx.x >> 6] = s;
  __syncthreads();
  if (threadIdx.x == 0) {
    float tot = red[0] + red[1] + red[2] + red[3];
    float fl = (sdiag == 0.0f) ? 1.0f : 0.0f;
    float deg = tot + fl;
    dinv2[row] = (deg > 0.0f) ? (1.0f / sqrtf(deg)) : 0.0f;
    dflg2[row] = fl;
  }
}

// ---------------- skinny matmul ----------------
template<int K, int NCOL, bool BIAS, bool RELU>
__global__ void k_mm_small(const float* __restrict__ A, const float* __restrict__ B,
                           const float* __restrict__ bias, float* __restrict__ out) {
  const int j = threadIdx.x;
  const int i = blockIdx.x * blockDim.y + threadIdx.y;
  const float* ar = A + (size_t)i * K;
  float acc = 0.f;
  #pragma unroll 8
  for (int k = 0; k < K; ++k) acc = fmaf(ar[k], B[(size_t)k * NCOL + j], acc);
  if (BIAS) acc += bias[j];
  if (RELU) acc = fmaxf(acc, 0.f);
  out[(size_t)i * NCOL + j] = acc;
}

// ---------------- layer1: h = relu(norm(AN)@XW1+b1); HW2 = h@w2 fused in-block ----------------
__global__ void k_an_mm1(const float* __restrict__ AN, const float* __restrict__ dinv,
                         const float* __restrict__ dflg, const float* __restrict__ XW1,
                         const float* __restrict__ bias1, const float* __restrict__ w2,
                         float* __restrict__ HW2) {
  __shared__ float hsh[4][64];
  const int j = threadIdx.x;    // 0..63
  const int ty = threadIdx.y;   // 0..3
  const int i = blockIdx.x * 4 + ty;
  const float di = dinv[i];
  const float* ar = AN + (size_t)i * N;
  float acc = 0.f;
  for (int k = 0; k < N; k += 4) {
    float4 a4 = *(const float4*)&ar[k];
    float4 d4 = *(const float4*)&dinv[k];
    acc = fmaf(a4.x * d4.x, XW1[(size_t)(k + 0) * 64 + j], acc);
    acc = fmaf(a4.y * d4.y, XW1[(size_t)(k + 1) * 64 + j], acc);
    acc = fmaf(a4.z * d4.z, XW1[(size_t)(k + 2) * 64 + j], acc);
    acc = fmaf(a4.w * d4.w, XW1[(size_t)(k + 3) * 64 + j], acc);
  }
  acc = fmaf(dflg[i] * dinv[i], XW1[(size_t)i * 64 + j], acc);
  acc = fmaf(di, acc, bias1[j]);
  acc = fmaxf(acc, 0.f);
  hsh[ty][j] = acc;
  __syncthreads();
  if (j < 32) {
    float s = 0.f;
    #pragma unroll 8
    for (int k2 = 0; k2 < 64; ++k2) s = fmaf(hsh[ty][k2], w2[k2 * 32 + j], s);
    HW2[(size_t)i * 32 + j] = s;
  }
}

// ---------------- layer2: out = norm(AN)@HW2 + b2 ----------------
template<int NCOL, bool RELU>
__global__ void k_an_mm(const float* __restrict__ BT, const float* __restrict__ dinv,
                        const float* __restrict__ dflg, const float* __restrict__ Bm,
                        const float* __restrict__ bias, float* __restrict__ out) {
  const int j = threadIdx.x;
  const int i = blockIdx.x * blockDim.y + threadIdx.y;
  const float di = dinv[i];
  const float* ar = BT + (size_t)i * N;
  float acc = 0.f;
  for (int k = 0; k < N; k += 4) {
    float4 a4 = *(const float4*)&ar[k];
    float4 d4 = *(const float4*)&dinv[k];
    acc = fmaf(a4.x * d4.x, Bm[(size_t)(k + 0) * NCOL + j], acc);
    acc = fmaf(a4.y * d4.y, Bm[(size_t)(k + 1) * NCOL + j], acc);
    acc = fmaf(a4.z * d4.z, Bm[(size_t)(k + 2) * NCOL + j], acc);
    acc = fmaf(a4.w * d4.w, Bm[(size_t)(k + 3) * NCOL + j], acc);
  }
  acc = fmaf(dflg[i] * dinv[i], Bm[(size_t)i * NCOL + j], acc);
  acc = fmaf(di, acc, bias[j]);
  if (RELU) acc = fmaxf(acc, 0.f);
  out[(size_t)i * NCOL + j] = acc;
}

// ---------------- launcher ----------------
extern "C" void kernel_launch(void* const* d_in, const int* in_sizes, int n_in,
                              void* d_out, int out_size, void* d_ws, size_t ws_size,
                              hipStream_t stream) {
  const float* x     = (const float*)d_in[0];
  const float* w1    = (const float*)d_in[22];
  const float* bias1 = (const float*)d_in[23];
  const float* w2    = (const float*)d_in[24];
  const float* bias2 = (const float*)d_in[25];
  float* out = (float*)d_out;
  float* ws  = (float*)d_ws;

  float* A    = ws + OFF_A;
  float* H1   = ws + OFF_H10;
  float* M0   = ws + OFF_M0;
  float* BT   = ws + OFF_BT;
  float* M1   = ws + OFF_M1;
  float* AN   = ws + OFF_AN;
  float* H2_0 = ws + OFF_H20;
  float* H2_1 = ws + OFF_H21;
  int*   gcol  = (int*)(ws + OFF_CSR);
  float* gval  = ws + OFF_CSR + (size_t)4 * CSRF;
  int*   crowT = (int*)(ws + OFF_CSR + (size_t)8 * CSRF);
  float* cvalT = ws + OFF_CSR + (size_t)8 * CSRF + CSC_MAXT * 1024;
  float* SC   = ws + OFF_SC;
  float *D0a = SC + SC_D0a, *F0a = SC + SC_F0a, *D1a = SC + SC_D1a, *F1a = SC + SC_F1a;
  float *D0b = SC + SC_D0b, *F0b = SC + SC_F0b, *D1b = SC + SC_D1b, *F1b = SC + SC_F1b;
  float *D2 = SC + SC_D2, *F2 = SC + SC_F2;
  float *DEGACC = SC + SC_DEG, *DIAGV = SC + SC_DGV;
  int*   gcnt = (int*)(SC + SC_GCNT);
  int*   ccnt = (int*)(SC + SC_CCNT);
  float *DEGA = SC + SC_DEGA, *DIAGA = SC + SC_DIAGA;
  float* ZC   = SC + SC_ZERO;
  float* XW1 = ws + OFF_XW1;
  float* HW2 = ws + OFF_HW2;

  hipMemsetAsync(A, 0, (size_t)5 * NN * sizeof(float), stream);

  dim3 b256(256), b16(16, 16);
  // independent: x @ w1
  k_mm_small<128, 64, false, false><<<256, dim3(64, 4), 0, stream>>>(x, w1, nullptr, XW1);

  k_scatter5<<<640, b256, 0, stream>>>((const int*)d_in[1], (const int*)d_in[2],
                                       (const int*)d_in[3], (const int*)d_in[4],
                                       (const int*)d_in[5], A);

  // conv1 (+ zeroes tc_emit/spmm2 counters in block 0)
  k_conv1_both<<<dim3(32, 32, 2), b16, 0, stream>>>(A,
      (const float*)d_in[6], (const float*)d_in[7],
      (const float*)d_in[14], (const float*)d_in[15], H1, ZC);
  k_conv2_both<<<dim3(17, 17, 2), b256, 0, stream>>>(H1,
      (const float*)d_in[8], (const float*)d_in[9],
      (const float*)d_in[16], (const float*)d_in[17], H2_0, H2_1);

  // attention apply + direct sparse emit (replaces tc_both + extract)
  k_tc_emit<<<dim3(32, 32, 2), b16, 0, stream>>>(H2_0, H2_1,
      (const float*)d_in[10], (const float*)d_in[11],
      (const float*)d_in[12], (const float*)d_in[13],
      (const float*)d_in[18], (const float*)d_in[19],
      (const float*)d_in[20], (const float*)d_in[21],
      A, gcol, gval, gcnt, crowT, cvalT, ccnt, DEGA, DIAGA);
  k_finA<<<8, b256, 0, stream>>>(DEGA, DIAGA, D0a, F0a, D1a, F1a);

  k_spmm<<<dim3(1024, 2), b256, 0, stream>>>(gcol, gval, gcnt,
      D0a, F0a, D1a, F1a, M0, BT, D0b, F0b, D1b, F1b);

  k_spmm2<<<dim3(128, 4), b256, 0, stream>>>(BT, D1b, F1b, crowT, cvalT, ccnt,
                                             M1, DEGACC, DIAGV);

  // combine + final deg (M1 deg computed inline from DEGACC/DIAGV)
  k_maxdeg<<<1024, b256, 0, stream>>>(M0, D0b, F0b, M1, DEGACC, DIAGV, AN, D2, F2);

  // GCN layers (h@w2 fused into layer-1 epilogue)
  k_an_mm1<<<256, dim3(64, 4), 0, stream>>>(AN, D2, F2, XW1, bias1, w2, HW2);
  k_an_mm<32, false><<<128, dim3(32, 8), 0, stream>>>(AN, D2, F2, HW2, bias2, out);
}

// Round 14
// 322.090 us; speedup vs baseline: 1.3258x; 1.0648x over previous
//
#include <hip/hip_runtime.h>
#include <math.h>

#define N 1024
#define NN (N*N)
#define NE 32768

// ---------------- workspace layout (floats) ----------------
#define OFF_A    ((size_t)0)
#define OFF_H10  ((size_t)(5*NN))
#define OFF_M0   ((size_t)(5*NN))
#define OFF_CSR  ((size_t)(7*NN))          // gcol/gval/crowT/cvalT (dead-H1 space, written by tc_emit)
#define OFF_BT   ((size_t)(9*NN))
#define OFF_M1   ((size_t)(10*NN))
#define OFF_AN   ((size_t)(11*NN))
#define OFF_H20  ((size_t)(13*NN))
#define OFF_H21  (OFF_H20 + 264196)
#define OFF_SC   (OFF_H21 + 264196)
// SC scalar region (floats). [SC_ZERO, SC_ZERO+10240) zeroed by conv1 block0.
#define SC_D0b   4096
#define SC_F0b   5120
#define SC_D1b   6144
#define SC_F1b   7168
#define SC_D2    8192
#define SC_F2    9216
#define SC_ZERO  10240
#define SC_DEG   10240      /* DEGACC (spmm2) 1024 */
#define SC_GCNT  11264      /* 4096 ints */
#define SC_CCNT  15360      /* 1024 ints */
#define SC_DEGA  16384      /* row-sum acc for A00/A10, 2048 */
#define SC_DIAGA 18432      /* diag of A00/A10, 2048 */
#define SC_DGV   20480      /* DIAGV (spmm2, densely written) 1024 */
#define SC_END   21504
#define OFF_XW1  (OFF_SC + SC_END)
#define OFF_HW2  (OFF_XW1 + 65536)

#define CSR_STRIDE 96
#define CSRF (1024 * CSR_STRIDE)
#define CSC_MAXT 80

// ---------------- fused: edge scatter (blocks 0..639) + x@w1 (blocks 640..895) ----------------
__global__ __launch_bounds__(256) void k_pre(const int* __restrict__ e0, const int* __restrict__ e1,
                           const int* __restrict__ e2, const int* __restrict__ e3,
                           const int* __restrict__ e4, float* __restrict__ A,
                           const float* __restrict__ x, const float* __restrict__ w1,
                           float* __restrict__ XW1) {
  const int b = blockIdx.x;
  if (b < 640) {
    int g = b * 256 + threadIdx.x;
    int seg = g >> 15;
    int k = g & 32767;
    const int* e = (seg == 0) ? e0 : (seg == 1) ? e1 : (seg == 2) ? e2 : (seg == 3) ? e3 : e4;
    atomicAdd(&A[(size_t)seg * NN + (size_t)e[k] * N + e[NE + k]], 1.0f);
  } else {
    const int j = threadIdx.x & 63;
    const int i = (b - 640) * 4 + (threadIdx.x >> 6);
    const float* ar = x + (size_t)i * 128;
    float acc = 0.f;
    #pragma unroll 8
    for (int k = 0; k < 128; ++k) acc = fmaf(ar[k], w1[(size_t)k * 64 + j], acc);
    XW1[(size_t)i * 64 + j] = acc;
  }
}

// ---------------- conv1 (pad=1) + relu + maxpool2 (+ counter zeroing in block 0) ----------------
template<int L>
__device__ __forceinline__ void conv1_body(const float* __restrict__ A,
    const float* __restrict__ W, const float* __restrict__ Bn, float* __restrict__ out) {
  __shared__ float sIn[L][34][35];
  __shared__ float sW[16 * L * 9];
  __shared__ float sB[16];
  int tid = threadIdx.y * 16 + threadIdx.x;
  for (int i = tid; i < 16 * L * 9; i += 256) sW[i] = W[i];
  if (tid < 16) sB[tid] = Bn[tid];
  const int x0 = blockIdx.x * 32 - 1;
  const int y0 = blockIdx.y * 32 - 1;
  for (int idx = tid; idx < L * 34 * 34; idx += 256) {
    int l = idx / (34 * 34);
    int rem = idx - l * 34 * 34;
    int r = rem / 34, c = rem - r * 34;
    int iy = y0 + r, ix = x0 + c;
    sIn[l][r][c] = (iy >= 0 && iy < N && ix >= 0 && ix < N) ? A[(size_t)l * NN + (size_t)iy * N + ix] : 0.f;
  }
  __syncthreads();
  const int tx = threadIdx.x, ty = threadIdx.y;
  float p[L][4][4];
  #pragma unroll
  for (int l = 0; l < L; ++l)
    #pragma unroll
    for (int r = 0; r < 4; ++r)
      #pragma unroll
      for (int c = 0; c < 4; ++c)
        p[l][r][c] = sIn[l][2 * ty + r][2 * tx + c];
  const int ox = blockIdx.x * 16 + tx;
  const int oy = blockIdx.y * 16 + ty;
  for (int oc = 0; oc < 16; ++oc) {
    float wr[L * 9];
    #pragma unroll
    for (int t = 0; t < L * 9; ++t) wr[t] = sW[oc * L * 9 + t];
    float m = -1e30f;
    #pragma unroll
    for (int dy = 0; dy < 2; ++dy)
      #pragma unroll
      for (int dx = 0; dx < 2; ++dx) {
        float s = 0.f;
        #pragma unroll
        for (int l = 0; l < L; ++l)
          #pragma unroll
          for (int ky = 0; ky < 3; ++ky)
            #pragma unroll
            for (int kx = 0; kx < 3; ++kx)
              s = fmaf(p[l][dy + ky][dx + kx], wr[l * 9 + ky * 3 + kx], s);
        m = fmaxf(m, s);
      }
    out[(size_t)oc * 262144 + (size_t)oy * 512 + ox] = fmaxf(m + sB[oc], 0.f);
  }
}

__global__ __launch_bounds__(256) void k_conv1_both(const float* __restrict__ Ab,
    const float* __restrict__ W0, const float* __restrict__ b0,
    const float* __restrict__ W1, const float* __restrict__ b1,
    float* __restrict__ H1b, float* __restrict__ ZC) {
  if (blockIdx.x == 0 && blockIdx.y == 0 && blockIdx.z == 0) {
    int tid = threadIdx.y * 16 + threadIdx.x;
    for (int i = tid; i < 10240; i += 256) ZC[i] = 0.f;
  }
  if (blockIdx.z == 0) conv1_body<2>(Ab, W0, b0, H1b);
  else                 conv1_body<3>(Ab + 2 * NN, W1, b1, H1b + 4 * NN);
}

// ---------------- conv2 (pad=2)+relu+maxpool2: DIRECT (R11 proven) ----------------
__global__ __launch_bounds__(256) void k_conv2_both(const float* __restrict__ H1b,
    const float* __restrict__ W0, const float* __restrict__ b0,
    const float* __restrict__ W1, const float* __restrict__ b1,
    float* __restrict__ H2_0, float* __restrict__ H2_1) {
  const int z = blockIdx.z;
  const float* in = H1b + (size_t)z * 4 * NN;
  const float* W  = z ? W1 : W0;
  const float* Bn = z ? b1 : b0;
  float* out = z ? H2_1 : H2_0;
  __shared__ float sW[4 * 16 * 9];
  __shared__ float sB[4];
  const int tid = threadIdx.x;
  for (int i = tid; i < 576; i += 256) sW[i] = W[i];
  if (tid < 4) sB[tid] = Bn[tid];
  __syncthreads();
  const int tx = tid & 15, ty = tid >> 4;
  const int ox = blockIdx.x * 16 + tx;
  const int oy = blockIdx.y * 16 + ty;
  if (ox >= 257 || oy >= 257) return;
  const int x0 = 2 * ox - 2;
  const int y0 = 2 * oy - 2;
  const bool c0ok = (x0 >= 0);
  const bool c1ok = (x0 + 2 < 512);
  float acc[4][2][2];
  #pragma unroll
  for (int oc = 0; oc < 4; ++oc)
    #pragma unroll
    for (int dy = 0; dy < 2; ++dy)
      #pragma unroll
      for (int dx = 0; dx < 2; ++dx) acc[oc][dy][dx] = 0.f;
  for (int ic = 0; ic < 16; ++ic) {
    const float* base = in + (size_t)ic * 262144;
    float p[4][4];
    #pragma unroll
    for (int r = 0; r < 4; ++r) {
      const int iy = y0 + r;
      const bool rowok = (iy >= 0 && iy < 512);
      float2 a = make_float2(0.f, 0.f), b = make_float2(0.f, 0.f);
      if (rowok) {
        const float* rp = base + (size_t)iy * 512;
        if (c0ok) a = *(const float2*)(rp + x0);
        if (c1ok) b = *(const float2*)(rp + x0 + 2);
      }
      p[r][0] = a.x; p[r][1] = a.y; p[r][2] = b.x; p[r][3] = b.y;
    }
    #pragma unroll
    for (int oc = 0; oc < 4; ++oc) {
      float wr[9];
      #pragma unroll
      for (int t = 0; t < 9; ++t) wr[t] = sW[oc * 144 + ic * 9 + t];
      #pragma unroll
      for (int ky = 0; ky < 3; ++ky)
        #pragma unroll
        for (int kx = 0; kx < 3; ++kx) {
          const float w = wr[ky * 3 + kx];
          #pragma unroll
          for (int dy = 0; dy < 2; ++dy)
            #pragma unroll
            for (int dx = 0; dx < 2; ++dx)
              acc[oc][dy][dx] = fmaf(p[dy + ky][dx + kx], w, acc[oc][dy][dx]);
        }
    }
  }
  #pragma unroll
  for (int oc = 0; oc < 4; ++oc) {
    float m = fmaxf(fmaxf(acc[oc][0][0], acc[oc][0][1]), fmaxf(acc[oc][1][0], acc[oc][1][1]));
    out[(size_t)oc * 66049 + (size_t)oy * 257 + ox] = fmaxf(m + sB[oc], 0.f);
  }
}

// ---------------- tconv1+tconv2+sigmoid + DIRECT sparse emit ----------------
__global__ __launch_bounds__(256) void k_tc_emit(
    const float* __restrict__ H2_0, const float* __restrict__ H2_1,
    const float* __restrict__ t1w0, const float* __restrict__ t1b0,
    const float* __restrict__ t2w0, const float* __restrict__ t2b0,
    const float* __restrict__ t1w1, const float* __restrict__ t1b1,
    const float* __restrict__ t2w1, const float* __restrict__ t2b1,
    const float* __restrict__ Ab,
    int* __restrict__ gcolA, float* __restrict__ gvalA, int* __restrict__ gcntA,
    int* __restrict__ crowT, float* __restrict__ cvalT, int* __restrict__ ccnt,
    float* __restrict__ DEGA, float* __restrict__ DIAGA) {
  const int z = blockIdx.z;
  const int L = 2 + z;
  const float* in  = z ? H2_1 : H2_0;
  const float* W1p = z ? t1w1 : t1w0;
  const float* B1p = z ? t1b1 : t1b0;
  const float* W2p = z ? t2w1 : t2w0;
  const float* B2p = z ? t2b1 : t2b0;
  __shared__ float sW1[256], sB1[16], sW2[192], sB2[3];
  int tid = threadIdx.y * 16 + threadIdx.x;
  sW1[tid] = W1p[tid];
  if (tid < 16) sB1[tid] = B1p[tid];
  for (int i = tid; i < L * 64; i += 256) sW2[i] = W2p[i];
  if (tid < L) sB2[tid] = B2p[tid];
  __syncthreads();
  const int n = blockIdx.x * 16 + threadIdx.x;   // 0..511
  const int m = blockIdx.y * 16 + threadIdx.y;   // 0..511
  const int p = m >> 1, q = n >> 1;
  const int f1y = 1 - (m & 1), f1x = 1 - (n & 1);
  float vin[4];
  #pragma unroll
  for (int ci = 0; ci < 4; ++ci) vin[ci] = in[(size_t)ci * 66049 + (size_t)p * 257 + q];
  float v16[16];
  #pragma unroll
  for (int c = 0; c < 16; ++c) {
    float s = sB1[c];
    #pragma unroll
    for (int ci = 0; ci < 4; ++ci)
      s = fmaf(vin[ci], sW1[c * 16 + ci * 4 + f1y * 2 + f1x], s);
    v16[c] = fmaxf(s, 0.f);
  }
  for (int l = 0; l < L; ++l) {
    const int mat = z * 2 + l;
    #pragma unroll
    for (int dy = 0; dy < 2; ++dy)
      #pragma unroll
      for (int dx = 0; dx < 2; ++dx) {
        float s = sB2[l];
        #pragma unroll
        for (int c = 0; c < 16; ++c)
          s = fmaf(v16[c], sW2[l * 64 + c * 4 + (1 - dy) * 2 + (1 - dx)], s);
        const float sg = 1.f / (1.f + expf(-s));
        const int grow = 2 * m + dy, gc = 2 * n + dx;
        const float av = Ab[(size_t)mat * NN + (size_t)grow * N + gc];
        const float v = av * sg;
        if (v != 0.f) {
          if (mat == 4) {
            int pp = atomicAdd(&ccnt[gc], 1);
            if (pp < CSC_MAXT) { crowT[pp * 1024 + gc] = grow; cvalT[pp * 1024 + gc] = v; }
          } else {
            int pp = atomicAdd(&gcntA[mat * 1024 + grow], 1);
            if (pp < CSR_STRIDE) {
              size_t rb = ((size_t)mat * 1024 + grow) * CSR_STRIDE;
              gcolA[rb + pp] = gc; gvalA[rb + pp] = v;
            }
          }
          if (mat == 0 || mat == 2) {     // left matrices ONLY
            atomicAdd(&DEGA[(mat >> 1) * 1024 + grow], v);
            if (grow == gc) DIAGA[(mat >> 1) * 1024 + grow] = v;
          }
        }
      }
  }
}

// ---------------- hop-1 double-sparse SpMM (left-norm computed inline from DEGA/DIAGA) ----------------
__device__ __forceinline__ float dinv_of(float deg, float diag, float* flout) {
  const float fl = (diag == 0.f) ? 1.f : 0.f;
  const float d = deg + fl;
  *flout = fl;
  return (d > 0.f) ? (1.f / sqrtf(d)) : 0.f;
}

__global__ __launch_bounds__(256) void k_spmm(
    const int* __restrict__ gcol, const float* __restrict__ gval, const int* __restrict__ gcnt,
    const float* __restrict__ DEGA, const float* __restrict__ DIAGA,
    float* __restrict__ M0, float* __restrict__ BT,
    float* __restrict__ D0b, float* __restrict__ F0b,
    float* __restrict__ D1b, float* __restrict__ F1b) {
  const int row = blockIdx.x;
  const int y = blockIdx.y;
  const int lm = y * 2, rm = y * 2 + 1;
  const int dbase = y * 1024;
  __shared__ __align__(16) float acc[1024];
  __shared__ int lcol[112];
  __shared__ float lw[112];
  __shared__ int lrc[112];
  __shared__ int cl;
  __shared__ float red[4];
  __shared__ float sdiag;
  ((float4*)acc)[threadIdx.x] = make_float4(0.f, 0.f, 0.f, 0.f);
  float flR;
  const float di = dinv_of(DEGA[dbase + row], DIAGA[dbase + row], &flR);
  const int cnt_l = min(gcnt[(size_t)lm * 1024 + row], CSR_STRIDE);
  const size_t lb = ((size_t)lm * 1024 + row) * CSR_STRIDE;
  if (threadIdx.x < cnt_l) {
    int k = gcol[lb + threadIdx.x];
    float flk;
    const float dk = dinv_of(DEGA[dbase + k], DIAGA[dbase + k], &flk);
    lcol[threadIdx.x] = k;
    lw[threadIdx.x] = di * gval[lb + threadIdx.x] * dk;
    lrc[threadIdx.x] = min(gcnt[(size_t)rm * 1024 + k], CSR_STRIDE);
  }
  if (threadIdx.x == 0) {
    int c = cnt_l;
    if (flR != 0.f) {
      lcol[c] = row; lw[c] = di * di;
      lrc[c] = min(gcnt[(size_t)rm * 1024 + row], CSR_STRIDE); ++c;
    }
    cl = c;
  }
  __syncthreads();
  const int sub = threadIdx.x >> 5, lane = threadIdx.x & 31;
  const int cle = cl;
  for (int e = sub; e < cle; e += 8) {
    const int k = lcol[e];
    const float w = lw[e];
    const int rc = lrc[e];
    const size_t rbv = ((size_t)rm * 1024 + k) * CSR_STRIDE;
    for (int t = lane; t < rc; t += 32)
      atomicAdd(&acc[gcol[rbv + t]], w * gval[rbv + t]);
  }
  __syncthreads();
  float4 o = ((const float4*)acc)[threadIdx.x];
  float* C = y ? BT : M0;
  ((float4*)(C + (size_t)row * N))[threadIdx.x] = o;
  if (threadIdx.x == (row >> 2)) sdiag = ((const float*)&o)[row & 3];
  float s = o.x + o.y + o.z + o.w;
  #pragma unroll
  for (int off = 32; off > 0; off >>= 1) s += __shfl_down(s, off, 64);
  if ((threadIdx.x & 63) == 0) red[threadIdx.x >> 6] = s;
  __syncthreads();
  if (threadIdx.x == 0) {
    float tot = red[0] + red[1] + red[2] + red[3];
    float fl = (sdiag == 0.f) ? 1.f : 0.f;
    float deg = tot + fl;
    float* D = y ? D1b : D0b;
    float* F = y ? F1b : F0b;
    D[row] = (deg > 0.f) ? (1.f / sqrtf(deg)) : 0.f;
    F[row] = fl;
  }
}

// ---------------- hop-2: 8 rows x 256 cols per block; CSC amortized ----------------
__global__ __launch_bounds__(256) void k_spmm2(const float* __restrict__ BT,
    const float* __restrict__ D1b, const float* __restrict__ F1b,
    const int* __restrict__ crowT, const float* __restrict__ cvalT, const int* __restrict__ ccnt,
    float* __restrict__ M1, float* __restrict__ DEGACC, float* __restrict__ DIAGV) {
  const int g0 = blockIdx.x << 3;
  const int j  = (blockIdx.y << 8) + threadIdx.x;
  __shared__ float bt[1024 * 9];
  __shared__ float wsum[4][8];
  const int tid = threadIdx.x;
  for (int kq = 0; kq < 4; ++kq) {
    const int k = (kq << 8) + tid;
    const float dv = D1b[k];
    #pragma unroll
    for (int row = 0; row < 8; ++row)
      bt[k * 9 + row] = BT[(size_t)(g0 + row) * N + k] * dv;
  }
  __syncthreads();
  if (tid < 8) {
    const int gr = g0 + tid;
    bt[gr * 9 + tid] += F1b[gr] * D1b[gr];
  }
  __syncthreads();
  int cn = ccnt[j];
  cn = min(cn, CSC_MAXT);
  float o[8];
  #pragma unroll
  for (int row = 0; row < 8; ++row) o[row] = 0.f;
  for (int t = 0; t < cn; ++t) {
    const int   r = crowT[t * 1024 + j];
    const float v = cvalT[t * 1024 + j];
    const int rb = r * 9;
    #pragma unroll
    for (int row = 0; row < 8; ++row)
      o[row] = fmaf(bt[rb + row], v, o[row]);
  }
  #pragma unroll
  for (int row = 0; row < 8; ++row) o[row] *= D1b[g0 + row];
  #pragma unroll
  for (int row = 0; row < 8; ++row)
    M1[(size_t)(g0 + row) * N + j] = o[row];
  if ((unsigned)(j - g0) < 8u) DIAGV[j] = o[j - g0];
  #pragma unroll
  for (int row = 0; row < 8; ++row) {
    float s = o[row];
    #pragma unroll
    for (int off = 32; off > 0; off >>= 1) s += __shfl_down(s, off, 64);
    if ((tid & 63) == 0) wsum[tid >> 6][row] = s;
  }
  __syncthreads();
  if (tid < 8) {
    float p = wsum[0][tid] + wsum[1][tid] + wsum[2][tid] + wsum[3][tid];
    atomicAdd(&DEGACC[g0 + tid], p);
  }
}

// ---------------- fused max(scale(M0), scale(M1)) + inline M1-deg + deg of result ----------------
__global__ __launch_bounds__(256) void k_maxdeg(const float* __restrict__ M0,
    const float* __restrict__ d0, const float* __restrict__ f0,
    const float* __restrict__ M1,
    const float* __restrict__ DEGACC, const float* __restrict__ DIAGV,
    float* __restrict__ Aout, float* __restrict__ dinv2, float* __restrict__ dflg2) {
  const int row = blockIdx.x;
  const int j4 = threadIdx.x;
  const float r0 = d0[row], fl0 = f0[row];
  const float flr = (DIAGV[row] == 0.f) ? 1.f : 0.f;
  const float degr = DEGACC[row] + flr;
  const float r1 = (degr > 0.f) ? (1.f / sqrtf(degr)) : 0.f;
  const float fl1 = flr;
  float4 a = ((const float4*)(M0 + (size_t)row * N))[j4];
  float4 b = ((const float4*)(M1 + (size_t)row * N))[j4];
  const float4 c0 = ((const float4*)d0)[j4];
  const float4 da = ((const float4*)DEGACC)[j4];
  const float4 gv = ((const float4*)DIAGV)[j4];
  float4 c1;
  {
    float fx = (gv.x == 0.f) ? 1.f : 0.f, dx_ = da.x + fx;
    float fy = (gv.y == 0.f) ? 1.f : 0.f, dy_ = da.y + fy;
    float fz = (gv.z == 0.f) ? 1.f : 0.f, dz_ = da.z + fz;
    float fw = (gv.w == 0.f) ? 1.f : 0.f, dw_ = da.w + fw;
    c1.x = (dx_ > 0.f) ? (1.f / sqrtf(dx_)) : 0.f;
    c1.y = (dy_ > 0.f) ? (1.f / sqrtf(dy_)) : 0.f;
    c1.z = (dz_ > 0.f) ? (1.f / sqrtf(dz_)) : 0.f;
    c1.w = (dw_ > 0.f) ? (1.f / sqrtf(dw_)) : 0.f;
  }
  int d = row - 4 * j4;
  if ((unsigned)d < 4u) { ((float*)&a)[d] += fl0; ((float*)&b)[d] += fl1; }
  float4 o;
  o.x = fmaxf(a.x * r0 * c0.x, b.x * r1 * c1.x);
  o.y = fmaxf(a.y * r0 * c0.y, b.y * r1 * c1.y);
  o.z = fmaxf(a.z * r0 * c0.z, b.z * r1 * c1.z);
  o.w = fmaxf(a.w * r0 * c0.w, b.w * r1 * c1.w);
  ((float4*)(Aout + (size_t)row * N))[j4] = o;
  __shared__ float sdiag;
  if ((unsigned)d < 4u) sdiag = ((float*)&o)[d];
  float s = o.x + o.y + o.z + o.w;
  #pragma unroll
  for (int off = 32; off > 0; off >>= 1) s += __shfl_down(s, off, 64);
  __shared__ float red[4];
  if ((threadIdx.x & 63) == 0) red[threadIdx.x >> 6] = s;
  __syncthreads();
  if (threadIdx.x == 0) {
    float tot = red[0] + red[1] + red[2] + red[3];
    float fl = (sdiag == 0.0f) ? 1.0f : 0.0f;
    float deg = tot + fl;
    dinv2[row] = (deg > 0.0f) ? (1.0f / sqrtf(deg)) : 0.0f;
    dflg2[row] = fl;
  }
}

// ---------------- layer1: h = relu(norm(AN)@XW1+b1); HW2 = h@w2 fused in-block ----------------
__global__ void k_an_mm1(const float* __restrict__ AN, const float* __restrict__ dinv,
                         const float* __restrict__ dflg, const float* __restrict__ XW1,
                         const float* __restrict__ bias1, const float* __restrict__ w2,
                         float* __restrict__ HW2) {
  __shared__ float hsh[4][64];
  const int j = threadIdx.x;    // 0..63
  const int ty = threadIdx.y;   // 0..3
  const int i = blockIdx.x * 4 + ty;
  const float di = dinv[i];
  const float* ar = AN + (size_t)i * N;
  float acc = 0.f;
  for (int k = 0; k < N; k += 4) {
    float4 a4 = *(const float4*)&ar[k];
    float4 d4 = *(const float4*)&dinv[k];
    acc = fmaf(a4.x * d4.x, XW1[(size_t)(k + 0) * 64 + j], acc);
    acc = fmaf(a4.y * d4.y, XW1[(size_t)(k + 1) * 64 + j], acc);
    acc = fmaf(a4.z * d4.z, XW1[(size_t)(k + 2) * 64 + j], acc);
    acc = fmaf(a4.w * d4.w, XW1[(size_t)(k + 3) * 64 + j], acc);
  }
  acc = fmaf(dflg[i] * dinv[i], XW1[(size_t)i * 64 + j], acc);
  acc = fmaf(di, acc, bias1[j]);
  acc = fmaxf(acc, 0.f);
  hsh[ty][j] = acc;
  __syncthreads();
  if (j < 32) {
    float s = 0.f;
    #pragma unroll 8
    for (int k2 = 0; k2 < 64; ++k2) s = fmaf(hsh[ty][k2], w2[k2 * 32 + j], s);
    HW2[(size_t)i * 32 + j] = s;
  }
}

// ---------------- layer2: out = norm(AN)@HW2 + b2 ----------------
template<int NCOL, bool RELU>
__global__ void k_an_mm(const float* __restrict__ BT, const float* __restrict__ dinv,
                        const float* __restrict__ dflg, const float* __restrict__ Bm,
                        const float* __restrict__ bias, float* __restrict__ out) {
  const int j = threadIdx.x;
  const int i = blockIdx.x * blockDim.y + threadIdx.y;
  const float di = dinv[i];
  const float* ar = BT + (size_t)i * N;
  float acc = 0.f;
  for (int k = 0; k < N; k += 4) {
    float4 a4 = *(const float4*)&ar[k];
    float4 d4 = *(const float4*)&dinv[k];
    acc = fmaf(a4.x * d4.x, Bm[(size_t)(k + 0) * NCOL + j], acc);
    acc = fmaf(a4.y * d4.y, Bm[(size_t)(k + 1) * NCOL + j], acc);
    acc = fmaf(a4.z * d4.z, Bm[(size_t)(k + 2) * NCOL + j], acc);
    acc = fmaf(a4.w * d4.w, Bm[(size_t)(k + 3) * NCOL + j], acc);
  }
  acc = fmaf(dflg[i] * dinv[i], Bm[(size_t)i * NCOL + j], acc);
  acc = fmaf(di, acc, bias[j]);
  if (RELU) acc = fmaxf(acc, 0.f);
  out[(size_t)i * NCOL + j] = acc;
}

// ---------------- launcher ----------------
extern "C" void kernel_launch(void* const* d_in, const int* in_sizes, int n_in,
                              void* d_out, int out_size, void* d_ws, size_t ws_size,
                              hipStream_t stream) {
  const float* x     = (const float*)d_in[0];
  const float* w1    = (const float*)d_in[22];
  const float* bias1 = (const float*)d_in[23];
  const float* w2    = (const float*)d_in[24];
  const float* bias2 = (const float*)d_in[25];
  float* out = (float*)d_out;
  float* ws  = (float*)d_ws;

  float* A    = ws + OFF_A;
  float* H1   = ws + OFF_H10;
  float* M0   = ws + OFF_M0;
  float* BT   = ws + OFF_BT;
  float* M1   = ws + OFF_M1;
  float* AN   = ws + OFF_AN;
  float* H2_0 = ws + OFF_H20;
  float* H2_1 = ws + OFF_H21;
  int*   gcol  = (int*)(ws + OFF_CSR);
  float* gval  = ws + OFF_CSR + (size_t)4 * CSRF;
  int*   crowT = (int*)(ws + OFF_CSR + (size_t)8 * CSRF);
  float* cvalT = ws + OFF_CSR + (size_t)8 * CSRF + CSC_MAXT * 1024;
  float* SC   = ws + OFF_SC;
  float *D0b = SC + SC_D0b, *F0b = SC + SC_F0b, *D1b = SC + SC_D1b, *F1b = SC + SC_F1b;
  float *D2 = SC + SC_D2, *F2 = SC + SC_F2;
  float *DEGACC = SC + SC_DEG, *DIAGV = SC + SC_DGV;
  int*   gcnt = (int*)(SC + SC_GCNT);
  int*   ccnt = (int*)(SC + SC_CCNT);
  float *DEGA = SC + SC_DEGA, *DIAGA = SC + SC_DIAGA;
  float* ZC   = SC + SC_ZERO;
  float* XW1 = ws + OFF_XW1;
  float* HW2 = ws + OFF_HW2;

  hipMemsetAsync(A, 0, (size_t)5 * NN * sizeof(float), stream);

  dim3 b256(256), b16(16, 16);
  // fused: edge scatter + x@w1
  k_pre<<<896, b256, 0, stream>>>((const int*)d_in[1], (const int*)d_in[2],
                                  (const int*)d_in[3], (const int*)d_in[4],
                                  (const int*)d_in[5], A, x, w1, XW1);

  // conv1 (+ zeroes tc_emit/spmm2 counters in block 0)
  k_conv1_both<<<dim3(32, 32, 2), b16, 0, stream>>>(A,
      (const float*)d_in[6], (const float*)d_in[7],
      (const float*)d_in[14], (const float*)d_in[15], H1, ZC);
  k_conv2_both<<<dim3(17, 17, 2), b256, 0, stream>>>(H1,
      (const float*)d_in[8], (const float*)d_in[9],
      (const float*)d_in[16], (const float*)d_in[17], H2_0, H2_1);

  // attention apply + direct sparse emit
  k_tc_emit<<<dim3(32, 32, 2), b16, 0, stream>>>(H2_0, H2_1,
      (const float*)d_in[10], (const float*)d_in[11],
      (const float*)d_in[12], (const float*)d_in[13],
      (const float*)d_in[18], (const float*)d_in[19],
      (const float*)d_in[20], (const float*)d_in[21],
      A, gcol, gval, gcnt, crowT, cvalT, ccnt, DEGA, DIAGA);

  // hop-1 (left-norm inline from DEGA/DIAGA; k_finA eliminated)
  k_spmm<<<dim3(1024, 2), b256, 0, stream>>>(gcol, gval, gcnt,
      DEGA, DIAGA, M0, BT, D0b, F0b, D1b, F1b);

  k_spmm2<<<dim3(128, 4), b256, 0, stream>>>(BT, D1b, F1b, crowT, cvalT, ccnt,
                                             M1, DEGACC, DIAGV);

  // combine + final deg
  k_maxdeg<<<1024, b256, 0, stream>>>(M0, D0b, F0b, M1, DEGACC, DIAGV, AN, D2, F2);

  // GCN layers
  k_an_mm1<<<256, dim3(64, 4), 0, stream>>>(AN, D2, F2, XW1, bias1, w2, HW2);
  k_an_mm<32, false><<<128, dim3(32, 8), 0, stream>>>(AN, D2, F2, HW2, bias2, out);
}